// Round 6
// baseline (327.309 us; speedup 1.0000x reference)
//
#include <hip/hip_runtime.h>
#include <math.h>

#define B_ 8
#define L_ 336
#define H_ 192
#define C_ 321
#define K_ 16
#define S_ 8
#define H2_ 97
#define OUT_ 3201
#define SEQLEN_ 528
#define BC_ (B_ * C_)
#define JD_ 136
#define MIXJ_ 291
#define NP_ 208            // padded N of DFT GEMM: 0..96 Re, 104..200 Im
#define MROWS_ 43656       // BC*17
#define MPAD_ 43712        // 683 * 64
#define NBLK_ 683

typedef float v2f __attribute__((ext_vector_type(2)));
typedef float v4f __attribute__((ext_vector_type(4)));
typedef __attribute__((ext_vector_type(8))) short bf16x8;
typedef __attribute__((ext_vector_type(4))) float f32x4;

#define TWO_PI_F 6.283185307179586f

// ws layout (float units)
static constexpr size_t OFF_SEQ    = 0;                                   // 1,355,904
static constexpr size_t OFF_MU     = OFF_SEQ + (size_t)BC_ * SEQLEN_;     // 2,568
static constexpr size_t OFF_STD    = OFF_MU + BC_;
static constexpr size_t OFF_U      = OFF_STD + BC_;                       // 349,248
static constexpr size_t OFF_WT2    = (OFF_U + (size_t)BC_ * JD_ + 3) & ~(size_t)3;
static constexpr size_t OFF_BPHI   = (OFF_WT2 + (size_t)2 * MIXJ_ * H2_ + 3) & ~(size_t)3;
static constexpr size_t OFF_BPLO   = OFF_BPHI + (size_t)NP_ * 192 / 2;    // bf16 counts
static constexpr size_t OFF_ROWS   = (OFF_BPLO + (size_t)NP_ * 192 / 2 + 3) & ~(size_t)3;
static constexpr size_t OFF_ROWSLO = OFF_ROWS + (size_t)MPAD_ * 192 / 2;
static constexpr size_t OFF_F      = OFF_ROWSLO + (size_t)MPAD_ * 192 / 2;
static constexpr size_t OFF_FILT   = OFF_ROWS;   // overlay: kFilt runs after kDFT

__device__ inline void split_bf16(float v, unsigned short& hh, unsigned short& ll) {
  unsigned u = __float_as_uint(v);
  unsigned hb = (u + 0x7FFFu + ((u >> 16) & 1u)) & 0xFFFF0000u;
  float fh = __uint_as_float(hb);
  float fl = v - fh;
  unsigned u2 = __float_as_uint(fl);
  unsigned lb = (u2 + 0x7FFFu + ((u2 >> 16) & 1u)) >> 16;
  hh = (unsigned short)(hb >> 16);
  ll = (unsigned short)lb;
}

// ---------------------------------------------------------------------------
// kStats: block = (b, 64-c tile), 256 thr = 4 waves over l-quarters.
// Outputs mu, std, U (p/cf folded in).  All x loads coalesced over c.
// ---------------------------------------------------------------------------
__launch_bounds__(256)
__global__ void kStats(const float* __restrict__ x, const float* __restrict__ cls_w,
                       const float* __restrict__ cls_bias,
                       const float* __restrict__ basic_state, const float* __restrict__ r,
                       const float* __restrict__ temperature,
                       float* __restrict__ mu, float* __restrict__ stdv,
                       float* __restrict__ U) {
  __shared__ float part[4][10][64];
  __shared__ float sp[64][S_];
  __shared__ float scf[64][K_];

  int b = blockIdx.x;
  int cb = blockIdx.y * 64;
  int lane = threadIdx.x & 63;
  int wv = threadIdx.x >> 6;
  int c = cb + lane;
  bool cok = c < C_;

  float sum = 0.f, sumsq = 0.f, a[S_];
#pragma unroll
  for (int s = 0; s < S_; s++) a[s] = 0.f;
  if (cok) {
    for (int l = wv * 84; l < wv * 84 + 84; l++) {
      float v = x[((size_t)b * L_ + l) * C_ + c];
      sum += v;
      sumsq = fmaf(v, v, sumsq);
#pragma unroll
      for (int s = 0; s < S_; s++) a[s] = fmaf(v, cls_w[s * L_ + l], a[s]);
    }
  }
  part[wv][0][lane] = sum;
  part[wv][1][lane] = sumsq;
#pragma unroll
  for (int s = 0; s < S_; s++) part[wv][2 + s][lane] = a[s];
  __syncthreads();

  if (threadIdx.x < 64 && cok) {
    float s0 = 0.f, s1 = 0.f, ac[S_];
#pragma unroll
    for (int s = 0; s < S_; s++) ac[s] = 0.f;
#pragma unroll
    for (int w = 0; w < 4; w++) {
      s0 += part[w][0][lane];
      s1 += part[w][1][lane];
#pragma unroll
      for (int s = 0; s < S_; s++) ac[s] += part[w][2 + s][lane];
    }
    float m = s0 * (1.f / L_);
    float var = fmaxf(s1 * (1.f / L_) - m * m, 0.f);
    float sd = sqrtf(var + 1e-8f);
    int bc = b * C_ + c;
    mu[bc] = m;
    stdv[bc] = sd;

    float lg[S_], mx = -1e30f;
#pragma unroll
    for (int s = 0; s < S_; s++) {
      lg[s] = ac[s] + cls_bias[s] + basic_state[c * S_ + s];
      mx = fmaxf(mx, lg[s]);
    }
    float den = 0.f;
#pragma unroll
    for (int s = 0; s < S_; s++) { float e = expf(lg[s] - mx); lg[s] = e; den += e; }
    float iden = 1.f / den;
#pragma unroll
    for (int s = 0; s < S_; s++) sp[lane][s] = lg[s] * iden;

    float it = 1.f / temperature[0];
    float aa[K_], am = it;
#pragma unroll
    for (int k = 0; k < K_; k++) {
      aa[k] = fabsf(r[(size_t)bc * K_ + k]) * it;
      am = fmaxf(am, aa[k]);
    }
    float den2 = expf(it - am);
#pragma unroll
    for (int k = 0; k < K_; k++) { float e = expf(aa[k] - am); aa[k] = e; den2 += e; }
    float iden2 = 1.f / den2;
#pragma unroll
    for (int k = 0; k < K_; k++) scf[lane][k] = aa[k] * iden2;
  }
  __syncthreads();

  for (int idx = threadIdx.x; idx < 64 * JD_; idx += 256) {
    int ci = idx / JD_;
    int j = idx - ci * JD_;
    if (cb + ci < C_) {
      int s = j / 17;
      int t = j - s * 17;
      float v = sp[ci][s];
      if (t < K_) v *= scf[ci][t];
      U[((size_t)b * C_ + cb + ci) * JD_ + j] = v;
    }
  }
}

// ---------------------------------------------------------------------------
// kSeqT: normalized seq via 32x32 LDS transpose tiles.  grid (B, 11, 17).
// ---------------------------------------------------------------------------
__launch_bounds__(256)
__global__ void kSeqT(const float* __restrict__ x, const float* __restrict__ y_hat,
                      const float* __restrict__ mu, const float* __restrict__ stdv,
                      float* __restrict__ seq) {
  __shared__ float tile[32][33];
  int b = blockIdx.x;
  int cb = blockIdx.y * 32;
  int tb = blockIdx.z * 32;
  int ci = threadIdx.x & 31;
  int q8 = threadIdx.x >> 5;
  int c = cb + ci;
  float m = 0.f, is = 0.f;
  if (c < C_) {
    m = mu[b * C_ + c];
    is = 1.f / stdv[b * C_ + c];
  }
#pragma unroll
  for (int q = 0; q < 4; q++) {
    int tt = q8 + q * 8;
    int t = tb + tt;
    float v = 0.f;
    if (c < C_ && t < SEQLEN_)
      v = (t < L_) ? x[((size_t)b * L_ + t) * C_ + c]
                   : y_hat[((size_t)b * H_ + (t - L_)) * C_ + c];
    tile[ci][tt] = (v - m) * is;
  }
  __syncthreads();
#pragma unroll
  for (int q = 0; q < 4; q++) {
    int cc = cb + q8 + q * 8;
    int t = tb + ci;
    if (cc < C_ && t < SEQLEN_)
      seq[((size_t)b * C_ + cc) * SEQLEN_ + t] = tile[q8 + q * 8][ci];
  }
}

// ---------------------------------------------------------------------------
// kPackB: DFT twiddle matrix, n-major [NP_][192], bf16 hi/lo split.
// cols 0..96: cos(2pi f h/192); 104..200: -sin(...); else 0.  Exact int phase.
// ---------------------------------------------------------------------------
__global__ void kPackB(unsigned short* __restrict__ bhi, unsigned short* __restrict__ blo) {
  int idx = blockIdx.x * 256 + threadIdx.x;
  if (idx >= NP_ * 192) return;
  int n = idx / 192;
  int h = idx - n * 192;
  float val = 0.f;
  if (n < H2_) {
    int ph = (n * h) % 192;
    val = cosf((TWO_PI_F / 192.f) * (float)ph);
  } else if (n >= 104 && n < 104 + H2_) {
    int ph = ((n - 104) * h) % 192;
    val = -sinf((TWO_PI_F / 192.f) * (float)ph);
  }
  unsigned short hh, ll;
  split_bf16(val, hh, ll);
  bhi[idx] = hh;
  blo[idx] = ll;
}

// ---------------------------------------------------------------------------
// kPackMixW: wT2[j*97+g] = (wr[g,j], wi[g,j])
// ---------------------------------------------------------------------------
__global__ void kPackMixW(const float* __restrict__ mwr, const float* __restrict__ mwi,
                          float2* __restrict__ wT2) {
  int idx = blockIdx.x * blockDim.x + threadIdx.x;
  if (idx >= MIXJ_ * H2_) return;
  int j = idx / H2_;
  int g = idx - j * H2_;
  wT2[idx] = make_float2(mwr[(size_t)g * MIXJ_ + j], mwi[(size_t)g * MIXJ_ + j]);
}

// ---------------------------------------------------------------------------
// kGather: leader rows (+sign) -> bf16 hi/lo planes, row m = bc*17 + k.
// ---------------------------------------------------------------------------
__launch_bounds__(64)
__global__ void kGather(const float* __restrict__ seq, const int* __restrict__ lead,
                        const int* __restrict__ shiftv, const float* __restrict__ r,
                        unsigned short* __restrict__ rhi, unsigned short* __restrict__ rlo) {
  int bc = blockIdx.x;
  int b = bc / C_;
  int lane = threadIdx.x;
#pragma unroll 1
  for (int k = 0; k < 17; k++) {
    float sg;
    const float* src;
    if (k < K_) {
      int ld = lead[(size_t)bc * K_ + k];
      int sh = shiftv[(size_t)bc * K_ + k];
      float rv = r[(size_t)bc * K_ + k];
      sg = (rv > 0.f) ? 1.f : ((rv < 0.f) ? -1.f : 0.f);
      src = seq + ((size_t)b * C_ + ld) * SEQLEN_ + (L_ - sh);
    } else {
      sg = 1.f;
      src = seq + (size_t)bc * SEQLEN_ + L_;
    }
    size_t mrow = (size_t)(bc * 17 + k) * 192;
#pragma unroll
    for (int p = 0; p < 3; p++) {
      int h = lane + p * 64;
      float v = src[h] * sg;
      unsigned short hh, ll;
      split_bf16(v, hh, ll);
      rhi[mrow + h] = hh;
      rlo[mrow + h] = ll;
    }
  }
}

// ---------------------------------------------------------------------------
// kDFT: GEMM F[M][NP_] = rows[M][192] @ Bp^T, bf16 split 3-term MFMA.
// block 256 thr = 4 waves, each wave one 16-row M-tile; no LDS.
// ---------------------------------------------------------------------------
__launch_bounds__(256)
__global__ void kDFT(const unsigned short* __restrict__ rhi,
                     const unsigned short* __restrict__ rlo,
                     const unsigned short* __restrict__ bhi,
                     const unsigned short* __restrict__ blo,
                     float* __restrict__ F) {
  int wv = threadIdx.x >> 6;
  int lane = threadIdx.x & 63;
  int m0 = blockIdx.x * 64 + wv * 16;
  int row = lane & 15;       // A row / B col / C col
  int kg = lane >> 4;        // k-group

  f32x4 acc[13];
#pragma unroll
  for (int nt = 0; nt < 13; nt++) acc[nt] = (f32x4){0.f, 0.f, 0.f, 0.f};

  const unsigned short* Ah = rhi + (size_t)(m0 + row) * 192 + kg * 8;
  const unsigned short* Al = rlo + (size_t)(m0 + row) * 192 + kg * 8;
  const unsigned short* Bh = bhi + (size_t)row * 192 + kg * 8;
  const unsigned short* Bl = blo + (size_t)row * 192 + kg * 8;

#pragma unroll
  for (int ks = 0; ks < 6; ks++) {
    bf16x8 ah = *(const bf16x8*)(Ah + ks * 32);
    bf16x8 al = *(const bf16x8*)(Al + ks * 32);
#pragma unroll
    for (int nt = 0; nt < 13; nt++) {
      bf16x8 bh = *(const bf16x8*)(Bh + (size_t)nt * 16 * 192 + ks * 32);
      bf16x8 bl = *(const bf16x8*)(Bl + (size_t)nt * 16 * 192 + ks * 32);
      acc[nt] = __builtin_amdgcn_mfma_f32_16x16x32_bf16(ah, bh, acc[nt], 0, 0, 0);
      acc[nt] = __builtin_amdgcn_mfma_f32_16x16x32_bf16(ah, bl, acc[nt], 0, 0, 0);
      acc[nt] = __builtin_amdgcn_mfma_f32_16x16x32_bf16(al, bh, acc[nt], 0, 0, 0);
    }
  }

  int crow0 = m0 + kg * 4;   // C row = (lane>>4)*4 + reg
#pragma unroll
  for (int nt = 0; nt < 13; nt++) {
#pragma unroll
    for (int rr = 0; rr < 4; rr++) {
      F[(size_t)(crow0 + rr) * NP_ + nt * 16 + row] = acc[nt][rr];
    }
  }
}

// ---------------------------------------------------------------------------
// kFilt: thread = o-column; W2 column in 136 VGPRs; u via wave-uniform scalar
// loads; 32 rows per block, 4 independent accumulators.  (unchanged R5)
// ---------------------------------------------------------------------------
__launch_bounds__(256)
__global__ void kFilt(const float* __restrict__ U, const float* __restrict__ mh_w,
                      const float* __restrict__ mh_b, float* __restrict__ filt) {
  int o = blockIdx.x * 256 + threadIdx.x;
  bool ook = o < OUT_;
  int oc = ook ? o : (OUT_ - 1);

  float w[JD_];
#pragma unroll
  for (int s = 0; s < S_; s++) {
#pragma unroll
    for (int t = 0; t < 17; t++) {
      w[s * 17 + t] = (t < K_)
          ? mh_w[(size_t)s * (K_ * OUT_) + (size_t)t * OUT_ + oc]
          : mh_b[(size_t)s * OUT_ + oc];
    }
  }

  int mBase = blockIdx.y * 32;
#pragma unroll 1
  for (int mi = 0; mi < 32; mi++) {
    int m = mBase + mi;
    if (m >= BC_) break;
    const float* up = U + (size_t)m * JD_;
    float a0 = 0.f, a1 = 0.f, a2 = 0.f, a3 = 0.f;
#pragma unroll
    for (int jj = 0; jj < 34; jj++) {
      a0 = fmaf(up[jj], w[jj], a0);
      a1 = fmaf(up[34 + jj], w[34 + jj], a1);
      a2 = fmaf(up[68 + jj], w[68 + jj], a2);
      a3 = fmaf(up[102 + jj], w[102 + jj], a3);
    }
    if (ook) filt[(size_t)m * OUT_ + o] = (a0 + a1) + (a2 + a3);
  }
}

// ---------------------------------------------------------------------------
// kPost: per bc (128 thr): filt combine -> mix matmul -> irfft -> epilogue.
// Tiny LDS (3.2 KB) -> high occupancy.
// ---------------------------------------------------------------------------
__launch_bounds__(128)
__global__ void kPost(const float* __restrict__ F, const float* __restrict__ filt,
                      const float* __restrict__ seq, const float* __restrict__ mu,
                      const float* __restrict__ stdv, const float2* __restrict__ wT2,
                      const float* __restrict__ mbr, const float* __restrict__ mbi,
                      float* __restrict__ out) {
  __shared__ __align__(16) v2f mix2[MIXJ_ + 1];
  __shared__ float zr[H2_], zi[H2_];

  int bc = blockIdx.x;
  int b = bc / C_;
  int c = bc - b * C_;
  int ff = threadIdx.x;
  bool fok = ff < H2_;

  if (fok) {
    float Fre[17], Fim[17];
#pragma unroll
    for (int k = 0; k < 17; k++) {
      size_t mr = (size_t)(bc * 17 + k) * NP_;
      Fre[k] = F[mr + ff];
      Fim[k] = F[mr + 104 + ff];
    }
    const float* fb = filt + (size_t)bc * OUT_;
    float yfR = Fre[16], yfI = Fim[16];
    float S1r = 0.f, S1i = 0.f, S2r = 0.f, S2i = 0.f, sg2 = 0.f;
#pragma unroll
    for (int k = 0; k < K_; k++) {
      float g1 = fb[k * H2_ + ff];
      float g2 = fb[(K_ + k) * H2_ + ff];
      float g12 = g1 * g2;
      S1r = fmaf(Fre[k], g1, S1r);
      S1i = fmaf(Fim[k], g1, S1i);
      S2r = fmaf(Fre[k], g12, S2r);
      S2i = fmaf(Fim[k], g12, S2i);
      sg2 += g2;
    }
    S2r = fmaf(-yfR, sg2, S2r);
    S2i = fmaf(-yfI, sg2, S2i);
    float g3 = fb[32 * H2_ + ff];
    mix2[ff] = (v2f){S1r, S1i};
    mix2[H2_ + ff] = (v2f){S2r, S2i};
    mix2[2 * H2_ + ff] = (v2f){yfR * g3, yfI * g3};
  }
  __syncthreads();

  if (fok) {
    float zfr = mbr[ff], zfi = mbi[ff];
    const float2* wf = wT2 + ff;
#pragma unroll 2
    for (int j = 0; j < MIXJ_ - 1; j += 2) {
      v4f mm = *(const v4f*)(mix2 + j);
      float2 a0 = wf[(size_t)j * H2_];
      float2 a1 = wf[(size_t)(j + 1) * H2_];
      zfr = fmaf(mm.x, a0.x, fmaf(-mm.y, a0.y, zfr));
      zfi = fmaf(mm.x, a0.y, fmaf(mm.y, a0.x, zfi));
      zfr = fmaf(mm.z, a1.x, fmaf(-mm.w, a1.y, zfr));
      zfi = fmaf(mm.z, a1.y, fmaf(mm.w, a1.x, zfi));
    }
    {
      int j = MIXJ_ - 1;
      v2f m2 = mix2[j];
      float2 a0 = wf[(size_t)j * H2_];
      zfr = fmaf(m2.x, a0.x, fmaf(-m2.y, a0.y, zfr));
      zfi = fmaf(m2.x, a0.y, fmaf(m2.y, a0.x, zfi));
    }
    zr[ff] = zfr;
    zi[ff] = zfi;
  }
  __syncthreads();

  if (ff < 96) {
    int h = ff;
    float m = mu[bc], sd = stdv[bc];
    float ang = (TWO_PI_F / 192.f) * (float)h;
    float cs, sn;
    sincosf(ang, &sn, &cs);
    float base = 0.5f * zr[0] + ((h & 1) ? -0.5f : 0.5f) * zr[96];
    float aE = 0.f, aO = 0.f;
    float cv = cs, sv = sn;
    for (int fq = 1; fq < 96; fq += 2) {
      aO = fmaf(zr[fq], cv, fmaf(-zi[fq], sv, aO));
      float nc = cv * cs - sv * sn;
      float ns = cv * sn + sv * cs;
      aE = fmaf(zr[fq + 1], nc, fmaf(-zi[fq + 1], ns, aE));
      cv = nc * cs - ns * sn;
      sv = nc * sn + ns * cs;
    }
    float y0 = (base + aE + aO) * (2.f / 192.f);
    float y1 = (base + aE - aO) * (2.f / 192.f);
    const float* sq = seq + (size_t)bc * SEQLEN_ + L_;
    out[((size_t)b * H_ + h) * C_ + c] = fmaf(sq[h] + y0, sd, m);
    out[((size_t)b * H_ + h + 96) * C_ + c] = fmaf(sq[h + 96] + y1, sd, m);
  }
}

// ---------------------------------------------------------------------------
extern "C" void kernel_launch(void* const* d_in, const int* in_sizes, int n_in,
                              void* d_out, int out_size, void* d_ws, size_t ws_size,
                              hipStream_t stream) {
  const float* x           = (const float*)d_in[0];
  const float* y_hat       = (const float*)d_in[1];
  const int*   lead        = (const int*)d_in[2];
  const int*   shiftv      = (const int*)d_in[3];
  const float* r           = (const float*)d_in[4];
  const float* temperature = (const float*)d_in[5];
  const float* cls_w       = (const float*)d_in[6];
  const float* cls_bias    = (const float*)d_in[7];
  const float* basic_state = (const float*)d_in[8];
  const float* mh_w        = (const float*)d_in[9];
  const float* mh_b        = (const float*)d_in[10];
  const float* mwr         = (const float*)d_in[11];
  const float* mwi         = (const float*)d_in[12];
  const float* mbr         = (const float*)d_in[13];
  const float* mbi         = (const float*)d_in[14];
  float* out = (float*)d_out;
  float* ws  = (float*)d_ws;

  unsigned short* bphi = (unsigned short*)(ws + OFF_BPHI);
  unsigned short* bplo = (unsigned short*)(ws + OFF_BPLO);
  unsigned short* rhi  = (unsigned short*)(ws + OFF_ROWS);
  unsigned short* rlo  = (unsigned short*)(ws + OFF_ROWSLO);

  dim3 gS(B_, 6);
  kStats<<<gS, 256, 0, stream>>>(x, cls_w, cls_bias, basic_state, r, temperature,
                                 ws + OFF_MU, ws + OFF_STD, ws + OFF_U);

  dim3 gT(B_, 11, 17);
  kSeqT<<<gT, 256, 0, stream>>>(x, y_hat, ws + OFF_MU, ws + OFF_STD, ws + OFF_SEQ);

  kPackB<<<(NP_ * 192 + 255) / 256, 256, 0, stream>>>(bphi, bplo);

  kPackMixW<<<(MIXJ_ * H2_ + 255) / 256, 256, 0, stream>>>(
      mwr, mwi, (float2*)(ws + OFF_WT2));

  kGather<<<BC_, 64, 0, stream>>>(ws + OFF_SEQ, lead, shiftv, r, rhi, rlo);

  kDFT<<<NBLK_, 256, 0, stream>>>(rhi, rlo, bphi, bplo, ws + OFF_F);

  dim3 gF((OUT_ + 255) / 256, (BC_ + 31) / 32);
  kFilt<<<gF, 256, 0, stream>>>(ws + OFF_U, mh_w, mh_b, ws + OFF_FILT);

  kPost<<<BC_, 128, 0, stream>>>(ws + OFF_F, ws + OFF_FILT, ws + OFF_SEQ,
                                 ws + OFF_MU, ws + OFF_STD,
                                 (const float2*)(ws + OFF_WT2), mbr, mbi, out);
}

// Round 7
// 296.904 us; speedup vs baseline: 1.1024x; 1.1024x over previous
//
#include <hip/hip_runtime.h>
#include <math.h>

#define B_ 8
#define L_ 336
#define H_ 192
#define C_ 321
#define K_ 16
#define S_ 8
#define H2_ 97
#define OUT_ 3201
#define SEQLEN_ 528
#define BC_ (B_ * C_)
#define JD_ 136
#define MIXJ_ 291
#define NP_ 208            // padded N of DFT GEMM: 0..96 Re, 104..200 Im
#define MROWS_ 43656       // BC*17
#define MPAD_ 43712        // 683 * 64
#define NBLK_ 683
#define KF_ 160            // filt GEMM K padded (136 -> 160)
#define MPADF_ 2576        // filt GEMM M padded (2568 -> 161*16)
#define NPADF_ 3264        // filt GEMM N padded (3201 -> 51*64)

typedef float v2f __attribute__((ext_vector_type(2)));
typedef float v4f __attribute__((ext_vector_type(4)));
typedef __attribute__((ext_vector_type(8))) short bf16x8;
typedef __attribute__((ext_vector_type(4))) float f32x4;

#define TWO_PI_F 6.283185307179586f

// ws layout (float units)
static constexpr size_t OFF_SEQ    = 0;
static constexpr size_t OFF_MU     = OFF_SEQ + (size_t)BC_ * SEQLEN_;
static constexpr size_t OFF_STD    = OFF_MU + BC_;
static constexpr size_t OFF_WT2    = (OFF_STD + BC_ + 3) & ~(size_t)3;
static constexpr size_t OFF_BPHI   = (OFF_WT2 + (size_t)2 * MIXJ_ * H2_ + 3) & ~(size_t)3;
static constexpr size_t OFF_BPLO   = OFF_BPHI + (size_t)NP_ * 192 / 2;
static constexpr size_t OFF_UHI    = (OFF_BPLO + (size_t)NP_ * 192 / 2 + 3) & ~(size_t)3;
static constexpr size_t OFF_ULO    = OFF_UHI + (size_t)MPADF_ * KF_ / 2;
static constexpr size_t OFF_W2HI   = OFF_ULO + (size_t)MPADF_ * KF_ / 2;
static constexpr size_t OFF_W2LO   = OFF_W2HI + (size_t)NPADF_ * KF_ / 2;
static constexpr size_t OFF_ROWS   = OFF_W2LO + (size_t)NPADF_ * KF_ / 2;
static constexpr size_t OFF_ROWSLO = OFF_ROWS + (size_t)MPAD_ * 192 / 2;
static constexpr size_t OFF_F      = OFF_ROWSLO + (size_t)MPAD_ * 192 / 2;
static constexpr size_t OFF_FILT   = OFF_ROWS;   // overlay: kFiltMM runs after kDFT

__device__ inline void split_bf16(float v, unsigned short& hh, unsigned short& ll) {
  unsigned u = __float_as_uint(v);
  unsigned hb = (u + 0x7FFFu + ((u >> 16) & 1u)) & 0xFFFF0000u;
  float fh = __uint_as_float(hb);
  float fl = v - fh;
  unsigned u2 = __float_as_uint(fl);
  unsigned lb = (u2 + 0x7FFFu + ((u2 >> 16) & 1u)) >> 16;
  hh = (unsigned short)(hb >> 16);
  ll = (unsigned short)lb;
}

// ---------------------------------------------------------------------------
// kStats: block = (b, 64-c tile), 256 thr = 4 waves over l-quarters.
// Outputs mu, std, and U directly as bf16 hi/lo planes [MPADF_][KF_].
// ---------------------------------------------------------------------------
__launch_bounds__(256)
__global__ void kStats(const float* __restrict__ x, const float* __restrict__ cls_w,
                       const float* __restrict__ cls_bias,
                       const float* __restrict__ basic_state, const float* __restrict__ r,
                       const float* __restrict__ temperature,
                       float* __restrict__ mu, float* __restrict__ stdv,
                       unsigned short* __restrict__ uhi, unsigned short* __restrict__ ulo) {
  __shared__ float part[4][10][64];
  __shared__ float sp[64][S_];
  __shared__ float scf[64][K_];

  int b = blockIdx.x;
  int cb = blockIdx.y * 64;
  int lane = threadIdx.x & 63;
  int wv = threadIdx.x >> 6;
  int c = cb + lane;
  bool cok = c < C_;

  float sum = 0.f, sumsq = 0.f, a[S_];
#pragma unroll
  for (int s = 0; s < S_; s++) a[s] = 0.f;
  if (cok) {
    for (int l = wv * 84; l < wv * 84 + 84; l++) {
      float v = x[((size_t)b * L_ + l) * C_ + c];
      sum += v;
      sumsq = fmaf(v, v, sumsq);
#pragma unroll
      for (int s = 0; s < S_; s++) a[s] = fmaf(v, cls_w[s * L_ + l], a[s]);
    }
  }
  part[wv][0][lane] = sum;
  part[wv][1][lane] = sumsq;
#pragma unroll
  for (int s = 0; s < S_; s++) part[wv][2 + s][lane] = a[s];
  __syncthreads();

  if (threadIdx.x < 64 && cok) {
    float s0 = 0.f, s1 = 0.f, ac[S_];
#pragma unroll
    for (int s = 0; s < S_; s++) ac[s] = 0.f;
#pragma unroll
    for (int w = 0; w < 4; w++) {
      s0 += part[w][0][lane];
      s1 += part[w][1][lane];
#pragma unroll
      for (int s = 0; s < S_; s++) ac[s] += part[w][2 + s][lane];
    }
    float m = s0 * (1.f / L_);
    float var = fmaxf(s1 * (1.f / L_) - m * m, 0.f);
    float sd = sqrtf(var + 1e-8f);
    int bc = b * C_ + c;
    mu[bc] = m;
    stdv[bc] = sd;

    float lg[S_], mx = -1e30f;
#pragma unroll
    for (int s = 0; s < S_; s++) {
      lg[s] = ac[s] + cls_bias[s] + basic_state[c * S_ + s];
      mx = fmaxf(mx, lg[s]);
    }
    float den = 0.f;
#pragma unroll
    for (int s = 0; s < S_; s++) { float e = expf(lg[s] - mx); lg[s] = e; den += e; }
    float iden = 1.f / den;
#pragma unroll
    for (int s = 0; s < S_; s++) sp[lane][s] = lg[s] * iden;

    float it = 1.f / temperature[0];
    float aa[K_], am = it;
#pragma unroll
    for (int k = 0; k < K_; k++) {
      aa[k] = fabsf(r[(size_t)bc * K_ + k]) * it;
      am = fmaxf(am, aa[k]);
    }
    float den2 = expf(it - am);
#pragma unroll
    for (int k = 0; k < K_; k++) { float e = expf(aa[k] - am); aa[k] = e; den2 += e; }
    float iden2 = 1.f / den2;
#pragma unroll
    for (int k = 0; k < K_; k++) scf[lane][k] = aa[k] * iden2;
  }
  __syncthreads();

  // U planes: row bc, k-dim padded to KF_ with zeros
  for (int idx = threadIdx.x; idx < 64 * KF_; idx += 256) {
    int ci = idx / KF_;
    int j = idx - ci * KF_;
    if (cb + ci < C_) {
      float v = 0.f;
      if (j < JD_) {
        int s = j / 17;
        int t = j - s * 17;
        v = sp[ci][s];
        if (t < K_) v *= scf[ci][t];
      }
      unsigned short hh, ll;
      split_bf16(v, hh, ll);
      size_t row = (size_t)(b * C_ + cb + ci) * KF_ + j;
      uhi[row] = hh;
      ulo[row] = ll;
    }
  }
}

// ---------------------------------------------------------------------------
// kSeqT: normalized seq via 32x32 LDS transpose tiles.  grid (B, 11, 17).
// ---------------------------------------------------------------------------
__launch_bounds__(256)
__global__ void kSeqT(const float* __restrict__ x, const float* __restrict__ y_hat,
                      const float* __restrict__ mu, const float* __restrict__ stdv,
                      float* __restrict__ seq) {
  __shared__ float tile[32][33];
  int b = blockIdx.x;
  int cb = blockIdx.y * 32;
  int tb = blockIdx.z * 32;
  int ci = threadIdx.x & 31;
  int q8 = threadIdx.x >> 5;
  int c = cb + ci;
  float m = 0.f, is = 0.f;
  if (c < C_) {
    m = mu[b * C_ + c];
    is = 1.f / stdv[b * C_ + c];
  }
#pragma unroll
  for (int q = 0; q < 4; q++) {
    int tt = q8 + q * 8;
    int t = tb + tt;
    float v = 0.f;
    if (c < C_ && t < SEQLEN_)
      v = (t < L_) ? x[((size_t)b * L_ + t) * C_ + c]
                   : y_hat[((size_t)b * H_ + (t - L_)) * C_ + c];
    tile[ci][tt] = (v - m) * is;
  }
  __syncthreads();
#pragma unroll
  for (int q = 0; q < 4; q++) {
    int cc = cb + q8 + q * 8;
    int t = tb + ci;
    if (cc < C_ && t < SEQLEN_)
      seq[((size_t)b * C_ + cc) * SEQLEN_ + t] = tile[q8 + q * 8][ci];
  }
}

// ---------------------------------------------------------------------------
// kPackB: DFT twiddle matrix, n-major [NP_][192], bf16 hi/lo split.
// ---------------------------------------------------------------------------
__global__ void kPackB(unsigned short* __restrict__ bhi, unsigned short* __restrict__ blo) {
  int idx = blockIdx.x * 256 + threadIdx.x;
  if (idx >= NP_ * 192) return;
  int n = idx / 192;
  int h = idx - n * 192;
  float val = 0.f;
  if (n < H2_) {
    int ph = (n * h) % 192;
    val = cosf((TWO_PI_F / 192.f) * (float)ph);
  } else if (n >= 104 && n < 104 + H2_) {
    int ph = ((n - 104) * h) % 192;
    val = -sinf((TWO_PI_F / 192.f) * (float)ph);
  }
  unsigned short hh, ll;
  split_bf16(val, hh, ll);
  bhi[idx] = hh;
  blo[idx] = ll;
}

// ---------------------------------------------------------------------------
// kPackW2: W2 n-major [NPADF_][KF_] bf16 hi/lo.  j = s*17+t; t<16 -> mh_w,
// t=16 -> mh_b; pads zero.
// ---------------------------------------------------------------------------
__global__ void kPackW2(const float* __restrict__ mh_w, const float* __restrict__ mh_b,
                        unsigned short* __restrict__ w2hi, unsigned short* __restrict__ w2lo) {
  int idx = blockIdx.x * 256 + threadIdx.x;
  if (idx >= NPADF_ * KF_) return;
  int n = idx / KF_;
  int k = idx - n * KF_;
  float v = 0.f;
  if (n < OUT_ && k < JD_) {
    int s = k / 17;
    int t = k - s * 17;
    v = (t < K_) ? mh_w[(size_t)s * (K_ * OUT_) + (size_t)t * OUT_ + n]
                 : mh_b[(size_t)s * OUT_ + n];
  }
  unsigned short hh, ll;
  split_bf16(v, hh, ll);
  w2hi[idx] = hh;
  w2lo[idx] = ll;
}

// ---------------------------------------------------------------------------
// kPackMixW: wT2[j*97+g] = (wr[g,j], wi[g,j])
// ---------------------------------------------------------------------------
__global__ void kPackMixW(const float* __restrict__ mwr, const float* __restrict__ mwi,
                          float2* __restrict__ wT2) {
  int idx = blockIdx.x * blockDim.x + threadIdx.x;
  if (idx >= MIXJ_ * H2_) return;
  int j = idx / H2_;
  int g = idx - j * H2_;
  wT2[idx] = make_float2(mwr[(size_t)g * MIXJ_ + j], mwi[(size_t)g * MIXJ_ + j]);
}

// ---------------------------------------------------------------------------
// kGather: leader rows (+sign) -> bf16 hi/lo planes, row m = bc*17 + k.
// ---------------------------------------------------------------------------
__launch_bounds__(128)
__global__ void kGather(const float* __restrict__ seq, const int* __restrict__ lead,
                        const int* __restrict__ shiftv, const float* __restrict__ r,
                        unsigned short* __restrict__ rhi, unsigned short* __restrict__ rlo) {
  int bc = blockIdx.x;
  int b = bc / C_;
  int lane = threadIdx.x;
#pragma unroll 1
  for (int k = 0; k < 17; k++) {
    float sg;
    const float* src;
    if (k < K_) {
      int ld = lead[(size_t)bc * K_ + k];
      int sh = shiftv[(size_t)bc * K_ + k];
      float rv = r[(size_t)bc * K_ + k];
      sg = (rv > 0.f) ? 1.f : ((rv < 0.f) ? -1.f : 0.f);
      src = seq + ((size_t)b * C_ + ld) * SEQLEN_ + (L_ - sh);
    } else {
      sg = 1.f;
      src = seq + (size_t)bc * SEQLEN_ + L_;
    }
    size_t mrow = (size_t)(bc * 17 + k) * 192;
#pragma unroll
    for (int p = 0; p < 2; p++) {
      int h = lane + p * 128;
      if (h < H_) {
        float v = src[h] * sg;
        unsigned short hh, ll;
        split_bf16(v, hh, ll);
        rhi[mrow + h] = hh;
        rlo[mrow + h] = ll;
      }
    }
  }
}

// ---------------------------------------------------------------------------
// kDFT: GEMM F[M][NP_] = rows[M][192] @ Bp^T, bf16 split 3-term MFMA.
// ---------------------------------------------------------------------------
__launch_bounds__(256)
__global__ void kDFT(const unsigned short* __restrict__ rhi,
                     const unsigned short* __restrict__ rlo,
                     const unsigned short* __restrict__ bhi,
                     const unsigned short* __restrict__ blo,
                     float* __restrict__ F) {
  int wv = threadIdx.x >> 6;
  int lane = threadIdx.x & 63;
  int m0 = blockIdx.x * 64 + wv * 16;
  int row = lane & 15;
  int kg = lane >> 4;

  f32x4 acc[13];
#pragma unroll
  for (int nt = 0; nt < 13; nt++) acc[nt] = (f32x4){0.f, 0.f, 0.f, 0.f};

  const unsigned short* Ah = rhi + (size_t)(m0 + row) * 192 + kg * 8;
  const unsigned short* Al = rlo + (size_t)(m0 + row) * 192 + kg * 8;
  const unsigned short* Bh = bhi + (size_t)row * 192 + kg * 8;
  const unsigned short* Bl = blo + (size_t)row * 192 + kg * 8;

#pragma unroll
  for (int ks = 0; ks < 6; ks++) {
    bf16x8 ah = *(const bf16x8*)(Ah + ks * 32);
    bf16x8 al = *(const bf16x8*)(Al + ks * 32);
#pragma unroll
    for (int nt = 0; nt < 13; nt++) {
      bf16x8 bh = *(const bf16x8*)(Bh + (size_t)nt * 16 * 192 + ks * 32);
      bf16x8 bl = *(const bf16x8*)(Bl + (size_t)nt * 16 * 192 + ks * 32);
      acc[nt] = __builtin_amdgcn_mfma_f32_16x16x32_bf16(ah, bh, acc[nt], 0, 0, 0);
      acc[nt] = __builtin_amdgcn_mfma_f32_16x16x32_bf16(ah, bl, acc[nt], 0, 0, 0);
      acc[nt] = __builtin_amdgcn_mfma_f32_16x16x32_bf16(al, bh, acc[nt], 0, 0, 0);
    }
  }

  int crow0 = m0 + kg * 4;
#pragma unroll
  for (int nt = 0; nt < 13; nt++) {
#pragma unroll
    for (int rr = 0; rr < 4; rr++) {
      F[(size_t)(crow0 + rr) * NP_ + nt * 16 + row] = acc[nt][rr];
    }
  }
}

// ---------------------------------------------------------------------------
// kFiltMM: filt GEMM on MFMA.  M=2568(p2576), N=3201(p3264), K=136(p160).
// Block 256 = 4 waves; wave = 16 m-rows x 64 n-cols; 5 K-steps; 3-term split.
// ---------------------------------------------------------------------------
__launch_bounds__(256)
__global__ void kFiltMM(const unsigned short* __restrict__ uhi,
                        const unsigned short* __restrict__ ulo,
                        const unsigned short* __restrict__ w2hi,
                        const unsigned short* __restrict__ w2lo,
                        float* __restrict__ filt) {
  int wv = threadIdx.x >> 6;
  int lane = threadIdx.x & 63;
  int m0 = (blockIdx.y * 4 + wv) * 16;
  if (m0 >= MPADF_) return;
  int n0 = blockIdx.x * 64;
  int col = lane & 15;
  int kg = lane >> 4;

  f32x4 acc[4];
#pragma unroll
  for (int nt = 0; nt < 4; nt++) acc[nt] = (f32x4){0.f, 0.f, 0.f, 0.f};

  const unsigned short* Ah = uhi + (size_t)(m0 + col) * KF_ + kg * 8;
  const unsigned short* Al = ulo + (size_t)(m0 + col) * KF_ + kg * 8;
  const unsigned short* Bh = w2hi + (size_t)(n0 + col) * KF_ + kg * 8;
  const unsigned short* Bl = w2lo + (size_t)(n0 + col) * KF_ + kg * 8;

#pragma unroll
  for (int ks = 0; ks < 5; ks++) {
    bf16x8 ah = *(const bf16x8*)(Ah + ks * 32);
    bf16x8 al = *(const bf16x8*)(Al + ks * 32);
#pragma unroll
    for (int nt = 0; nt < 4; nt++) {
      bf16x8 bh = *(const bf16x8*)(Bh + (size_t)nt * 16 * KF_ + ks * 32);
      bf16x8 bl = *(const bf16x8*)(Bl + (size_t)nt * 16 * KF_ + ks * 32);
      acc[nt] = __builtin_amdgcn_mfma_f32_16x16x32_bf16(ah, bh, acc[nt], 0, 0, 0);
      acc[nt] = __builtin_amdgcn_mfma_f32_16x16x32_bf16(ah, bl, acc[nt], 0, 0, 0);
      acc[nt] = __builtin_amdgcn_mfma_f32_16x16x32_bf16(al, bh, acc[nt], 0, 0, 0);
    }
  }

  int crow0 = m0 + kg * 4;
#pragma unroll
  for (int nt = 0; nt < 4; nt++) {
    int o = n0 + nt * 16 + col;
    if (o < OUT_) {
#pragma unroll
      for (int rr = 0; rr < 4; rr++) {
        int m = crow0 + rr;
        if (m < BC_) filt[(size_t)m * OUT_ + o] = acc[nt][rr];
      }
    }
  }
}

// ---------------------------------------------------------------------------
// kPost: per bc (128 thr): filt combine -> mix matmul -> irfft -> epilogue.
// ---------------------------------------------------------------------------
__launch_bounds__(128)
__global__ void kPost(const float* __restrict__ F, const float* __restrict__ filt,
                      const float* __restrict__ seq, const float* __restrict__ mu,
                      const float* __restrict__ stdv, const float2* __restrict__ wT2,
                      const float* __restrict__ mbr, const float* __restrict__ mbi,
                      float* __restrict__ out) {
  __shared__ __align__(16) v2f mix2[MIXJ_ + 1];
  __shared__ float zr[H2_], zi[H2_];

  int bc = blockIdx.x;
  int b = bc / C_;
  int c = bc - b * C_;
  int ff = threadIdx.x;
  bool fok = ff < H2_;

  if (fok) {
    float Fre[17], Fim[17];
#pragma unroll
    for (int k = 0; k < 17; k++) {
      size_t mr = (size_t)(bc * 17 + k) * NP_;
      Fre[k] = F[mr + ff];
      Fim[k] = F[mr + 104 + ff];
    }
    const float* fb = filt + (size_t)bc * OUT_;
    float yfR = Fre[16], yfI = Fim[16];
    float S1r = 0.f, S1i = 0.f, S2r = 0.f, S2i = 0.f, sg2 = 0.f;
#pragma unroll
    for (int k = 0; k < K_; k++) {
      float g1 = fb[k * H2_ + ff];
      float g2 = fb[(K_ + k) * H2_ + ff];
      float g12 = g1 * g2;
      S1r = fmaf(Fre[k], g1, S1r);
      S1i = fmaf(Fim[k], g1, S1i);
      S2r = fmaf(Fre[k], g12, S2r);
      S2i = fmaf(Fim[k], g12, S2i);
      sg2 += g2;
    }
    S2r = fmaf(-yfR, sg2, S2r);
    S2i = fmaf(-yfI, sg2, S2i);
    float g3 = fb[32 * H2_ + ff];
    mix2[ff] = (v2f){S1r, S1i};
    mix2[H2_ + ff] = (v2f){S2r, S2i};
    mix2[2 * H2_ + ff] = (v2f){yfR * g3, yfI * g3};
  }
  __syncthreads();

  if (fok) {
    float zfr = mbr[ff], zfi = mbi[ff];
    const float2* wf = wT2 + ff;
#pragma unroll 2
    for (int j = 0; j < MIXJ_ - 1; j += 2) {
      v4f mm = *(const v4f*)(mix2 + j);
      float2 a0 = wf[(size_t)j * H2_];
      float2 a1 = wf[(size_t)(j + 1) * H2_];
      zfr = fmaf(mm.x, a0.x, fmaf(-mm.y, a0.y, zfr));
      zfi = fmaf(mm.x, a0.y, fmaf(mm.y, a0.x, zfi));
      zfr = fmaf(mm.z, a1.x, fmaf(-mm.w, a1.y, zfr));
      zfi = fmaf(mm.z, a1.y, fmaf(mm.w, a1.x, zfi));
    }
    {
      int j = MIXJ_ - 1;
      v2f m2 = mix2[j];
      float2 a0 = wf[(size_t)j * H2_];
      zfr = fmaf(m2.x, a0.x, fmaf(-m2.y, a0.y, zfr));
      zfi = fmaf(m2.x, a0.y, fmaf(m2.y, a0.x, zfi));
    }
    zr[ff] = zfr;
    zi[ff] = zfi;
  }
  __syncthreads();

  if (ff < 96) {
    int h = ff;
    float m = mu[bc], sd = stdv[bc];
    float ang = (TWO_PI_F / 192.f) * (float)h;
    float cs, sn;
    sincosf(ang, &sn, &cs);
    float base = 0.5f * zr[0] + ((h & 1) ? -0.5f : 0.5f) * zr[96];
    float aE = 0.f, aO = 0.f;
    float cv = cs, sv = sn;
    for (int fq = 1; fq < 96; fq += 2) {
      aO = fmaf(zr[fq], cv, fmaf(-zi[fq], sv, aO));
      float nc = cv * cs - sv * sn;
      float ns = cv * sn + sv * cs;
      aE = fmaf(zr[fq + 1], nc, fmaf(-zi[fq + 1], ns, aE));
      cv = nc * cs - ns * sn;
      sv = nc * sn + ns * cs;
    }
    float y0 = (base + aE + aO) * (2.f / 192.f);
    float y1 = (base + aE - aO) * (2.f / 192.f);
    const float* sq = seq + (size_t)bc * SEQLEN_ + L_;
    out[((size_t)b * H_ + h) * C_ + c] = fmaf(sq[h] + y0, sd, m);
    out[((size_t)b * H_ + h + 96) * C_ + c] = fmaf(sq[h + 96] + y1, sd, m);
  }
}

// ---------------------------------------------------------------------------
extern "C" void kernel_launch(void* const* d_in, const int* in_sizes, int n_in,
                              void* d_out, int out_size, void* d_ws, size_t ws_size,
                              hipStream_t stream) {
  const float* x           = (const float*)d_in[0];
  const float* y_hat       = (const float*)d_in[1];
  const int*   lead        = (const int*)d_in[2];
  const int*   shiftv      = (const int*)d_in[3];
  const float* r           = (const float*)d_in[4];
  const float* temperature = (const float*)d_in[5];
  const float* cls_w       = (const float*)d_in[6];
  const float* cls_bias    = (const float*)d_in[7];
  const float* basic_state = (const float*)d_in[8];
  const float* mh_w        = (const float*)d_in[9];
  const float* mh_b        = (const float*)d_in[10];
  const float* mwr         = (const float*)d_in[11];
  const float* mwi         = (const float*)d_in[12];
  const float* mbr         = (const float*)d_in[13];
  const float* mbi         = (const float*)d_in[14];
  float* out = (float*)d_out;
  float* ws  = (float*)d_ws;

  unsigned short* bphi = (unsigned short*)(ws + OFF_BPHI);
  unsigned short* bplo = (unsigned short*)(ws + OFF_BPLO);
  unsigned short* uhi  = (unsigned short*)(ws + OFF_UHI);
  unsigned short* ulo  = (unsigned short*)(ws + OFF_ULO);
  unsigned short* w2hi = (unsigned short*)(ws + OFF_W2HI);
  unsigned short* w2lo = (unsigned short*)(ws + OFF_W2LO);
  unsigned short* rhi  = (unsigned short*)(ws + OFF_ROWS);
  unsigned short* rlo  = (unsigned short*)(ws + OFF_ROWSLO);

  dim3 gS(B_, 6);
  kStats<<<gS, 256, 0, stream>>>(x, cls_w, cls_bias, basic_state, r, temperature,
                                 ws + OFF_MU, ws + OFF_STD, uhi, ulo);

  dim3 gT(B_, 11, 17);
  kSeqT<<<gT, 256, 0, stream>>>(x, y_hat, ws + OFF_MU, ws + OFF_STD, ws + OFF_SEQ);

  kPackB<<<(NP_ * 192 + 255) / 256, 256, 0, stream>>>(bphi, bplo);

  kPackW2<<<(NPADF_ * KF_ + 255) / 256, 256, 0, stream>>>(mh_w, mh_b, w2hi, w2lo);

  kPackMixW<<<(MIXJ_ * H2_ + 255) / 256, 256, 0, stream>>>(
      mwr, mwi, (float2*)(ws + OFF_WT2));

  kGather<<<BC_, 128, 0, stream>>>(ws + OFF_SEQ, lead, shiftv, r, rhi, rlo);

  kDFT<<<NBLK_, 256, 0, stream>>>(rhi, rlo, bphi, bplo, ws + OFF_F);

  dim3 gFM(NPADF_ / 64, (MPADF_ / 16 + 3) / 4);
  kFiltMM<<<gFM, 256, 0, stream>>>(uhi, ulo, w2hi, w2lo, ws + OFF_FILT);

  kPost<<<BC_, 128, 0, stream>>>(ws + OFF_F, ws + OFF_FILT, ws + OFF_SEQ,
                                 ws + OFF_MU, ws + OFF_STD,
                                 (const float2*)(ws + OFF_WT2), mbr, mbi, out);
}

// Round 8
// 255.539 us; speedup vs baseline: 1.2809x; 1.1619x over previous
//
#include <hip/hip_runtime.h>
#include <math.h>

#define B_ 8
#define L_ 336
#define H_ 192
#define C_ 321
#define K_ 16
#define S_ 8
#define H2_ 97
#define OUT_ 3201
#define SEQLEN_ 528
#define BC_ (B_ * C_)
#define JD_ 136
#define MIXJ_ 291
#define NP_ 208
#define MROWS_ 43656
#define MPAD_ 43712
#define NBLK_ 683
#define KF_ 160
#define MPADF_ 2576
#define NPADF_ 3264

typedef float v2f __attribute__((ext_vector_type(2)));
typedef float v4f __attribute__((ext_vector_type(4)));
typedef __attribute__((ext_vector_type(8))) short bf16x8;
typedef __attribute__((ext_vector_type(4))) float f32x4;

#define TWO_PI_F 6.283185307179586f

// ws layout (float units)
static constexpr size_t OFF_SEQ    = 0;
static constexpr size_t OFF_MU     = OFF_SEQ + (size_t)BC_ * SEQLEN_;
static constexpr size_t OFF_STD    = OFF_MU + BC_;
static constexpr size_t OFF_WT2    = (OFF_STD + BC_ + 3) & ~(size_t)3;
static constexpr size_t OFF_BPHI   = (OFF_WT2 + (size_t)2 * MIXJ_ * H2_ + 3) & ~(size_t)3;
static constexpr size_t OFF_BPLO   = OFF_BPHI + (size_t)NP_ * 192 / 2;
static constexpr size_t OFF_UHI    = (OFF_BPLO + (size_t)NP_ * 192 / 2 + 3) & ~(size_t)3;
static constexpr size_t OFF_ULO    = OFF_UHI + (size_t)MPADF_ * KF_ / 2;
static constexpr size_t OFF_W2HI   = OFF_ULO + (size_t)MPADF_ * KF_ / 2;
static constexpr size_t OFF_W2LO   = OFF_W2HI + (size_t)NPADF_ * KF_ / 2;
static constexpr size_t OFF_ROWS   = OFF_W2LO + (size_t)NPADF_ * KF_ / 2;
static constexpr size_t OFF_ROWSLO = OFF_ROWS + (size_t)MPAD_ * 192 / 2;
static constexpr size_t OFF_F      = OFF_ROWSLO + (size_t)MPAD_ * 192 / 2;
static constexpr size_t OFF_FILT   = OFF_ROWS;   // overlay: kFiltMM after kDFT

__device__ inline void split_bf16(float v, unsigned short& hh, unsigned short& ll) {
  unsigned u = __float_as_uint(v);
  unsigned hb = (u + 0x7FFFu + ((u >> 16) & 1u)) & 0xFFFF0000u;
  float fh = __uint_as_float(hb);
  float fl = v - fh;
  unsigned u2 = __float_as_uint(fl);
  unsigned lb = (u2 + 0x7FFFu + ((u2 >> 16) & 1u)) >> 16;
  hh = (unsigned short)(hb >> 16);
  ll = (unsigned short)lb;
}

// ---------------------------------------------------------------------------
__launch_bounds__(256)
__global__ void kStats(const float* __restrict__ x, const float* __restrict__ cls_w,
                       const float* __restrict__ cls_bias,
                       const float* __restrict__ basic_state, const float* __restrict__ r,
                       const float* __restrict__ temperature,
                       float* __restrict__ mu, float* __restrict__ stdv,
                       unsigned short* __restrict__ uhi, unsigned short* __restrict__ ulo) {
  __shared__ float part[4][10][64];
  __shared__ float sp[64][S_];
  __shared__ float scf[64][K_];

  int b = blockIdx.x;
  int cb = blockIdx.y * 64;
  int lane = threadIdx.x & 63;
  int wv = threadIdx.x >> 6;
  int c = cb + lane;
  bool cok = c < C_;

  float sum = 0.f, sumsq = 0.f, a[S_];
#pragma unroll
  for (int s = 0; s < S_; s++) a[s] = 0.f;
  if (cok) {
    for (int l = wv * 84; l < wv * 84 + 84; l++) {
      float v = x[((size_t)b * L_ + l) * C_ + c];
      sum += v;
      sumsq = fmaf(v, v, sumsq);
#pragma unroll
      for (int s = 0; s < S_; s++) a[s] = fmaf(v, cls_w[s * L_ + l], a[s]);
    }
  }
  part[wv][0][lane] = sum;
  part[wv][1][lane] = sumsq;
#pragma unroll
  for (int s = 0; s < S_; s++) part[wv][2 + s][lane] = a[s];
  __syncthreads();

  if (threadIdx.x < 64 && cok) {
    float s0 = 0.f, s1 = 0.f, ac[S_];
#pragma unroll
    for (int s = 0; s < S_; s++) ac[s] = 0.f;
#pragma unroll
    for (int w = 0; w < 4; w++) {
      s0 += part[w][0][lane];
      s1 += part[w][1][lane];
#pragma unroll
      for (int s = 0; s < S_; s++) ac[s] += part[w][2 + s][lane];
    }
    float m = s0 * (1.f / L_);
    float var = fmaxf(s1 * (1.f / L_) - m * m, 0.f);
    float sd = sqrtf(var + 1e-8f);
    int bc = b * C_ + c;
    mu[bc] = m;
    stdv[bc] = sd;

    float lg[S_], mx = -1e30f;
#pragma unroll
    for (int s = 0; s < S_; s++) {
      lg[s] = ac[s] + cls_bias[s] + basic_state[c * S_ + s];
      mx = fmaxf(mx, lg[s]);
    }
    float den = 0.f;
#pragma unroll
    for (int s = 0; s < S_; s++) { float e = expf(lg[s] - mx); lg[s] = e; den += e; }
    float iden = 1.f / den;
#pragma unroll
    for (int s = 0; s < S_; s++) sp[lane][s] = lg[s] * iden;

    float it = 1.f / temperature[0];
    float aa[K_], am = it;
#pragma unroll
    for (int k = 0; k < K_; k++) {
      aa[k] = fabsf(r[(size_t)bc * K_ + k]) * it;
      am = fmaxf(am, aa[k]);
    }
    float den2 = expf(it - am);
#pragma unroll
    for (int k = 0; k < K_; k++) { float e = expf(aa[k] - am); aa[k] = e; den2 += e; }
    float iden2 = 1.f / den2;
#pragma unroll
    for (int k = 0; k < K_; k++) scf[lane][k] = aa[k] * iden2;
  }
  __syncthreads();

  for (int idx = threadIdx.x; idx < 64 * KF_; idx += 256) {
    int ci = idx / KF_;
    int j = idx - ci * KF_;
    if (cb + ci < C_) {
      float v = 0.f;
      if (j < JD_) {
        int s = j / 17;
        int t = j - s * 17;
        v = sp[ci][s];
        if (t < K_) v *= scf[ci][t];
      }
      unsigned short hh, ll;
      split_bf16(v, hh, ll);
      size_t row = (size_t)(b * C_ + cb + ci) * KF_ + j;
      uhi[row] = hh;
      ulo[row] = ll;
    }
  }
}

// ---------------------------------------------------------------------------
__launch_bounds__(256)
__global__ void kSeqT(const float* __restrict__ x, const float* __restrict__ y_hat,
                      const float* __restrict__ mu, const float* __restrict__ stdv,
                      float* __restrict__ seq) {
  __shared__ float tile[32][33];
  int b = blockIdx.x;
  int cb = blockIdx.y * 32;
  int tb = blockIdx.z * 32;
  int ci = threadIdx.x & 31;
  int q8 = threadIdx.x >> 5;
  int c = cb + ci;
  float m = 0.f, is = 0.f;
  if (c < C_) {
    m = mu[b * C_ + c];
    is = 1.f / stdv[b * C_ + c];
  }
#pragma unroll
  for (int q = 0; q < 4; q++) {
    int tt = q8 + q * 8;
    int t = tb + tt;
    float v = 0.f;
    if (c < C_ && t < SEQLEN_)
      v = (t < L_) ? x[((size_t)b * L_ + t) * C_ + c]
                   : y_hat[((size_t)b * H_ + (t - L_)) * C_ + c];
    tile[ci][tt] = (v - m) * is;
  }
  __syncthreads();
#pragma unroll
  for (int q = 0; q < 4; q++) {
    int cc = cb + q8 + q * 8;
    int t = tb + ci;
    if (cc < C_ && t < SEQLEN_)
      seq[((size_t)b * C_ + cc) * SEQLEN_ + t] = tile[q8 + q * 8][ci];
  }
}

// ---------------------------------------------------------------------------
__global__ void kPackB(unsigned short* __restrict__ bhi, unsigned short* __restrict__ blo) {
  int idx = blockIdx.x * 256 + threadIdx.x;
  if (idx >= NP_ * 192) return;
  int n = idx / 192;
  int h = idx - n * 192;
  float val = 0.f;
  if (n < H2_) {
    int ph = (n * h) % 192;
    val = cosf((TWO_PI_F / 192.f) * (float)ph);
  } else if (n >= 104 && n < 104 + H2_) {
    int ph = ((n - 104) * h) % 192;
    val = -sinf((TWO_PI_F / 192.f) * (float)ph);
  }
  unsigned short hh, ll;
  split_bf16(val, hh, ll);
  bhi[idx] = hh;
  blo[idx] = ll;
}

// ---------------------------------------------------------------------------
__global__ void kPackW2(const float* __restrict__ mh_w, const float* __restrict__ mh_b,
                        unsigned short* __restrict__ w2hi, unsigned short* __restrict__ w2lo) {
  int idx = blockIdx.x * 256 + threadIdx.x;
  if (idx >= NPADF_ * KF_) return;
  int n = idx / KF_;
  int k = idx - n * KF_;
  float v = 0.f;
  if (n < OUT_ && k < JD_) {
    int s = k / 17;
    int t = k - s * 17;
    v = (t < K_) ? mh_w[(size_t)s * (K_ * OUT_) + (size_t)t * OUT_ + n]
                 : mh_b[(size_t)s * OUT_ + n];
  }
  unsigned short hh, ll;
  split_bf16(v, hh, ll);
  w2hi[idx] = hh;
  w2lo[idx] = ll;
}

// ---------------------------------------------------------------------------
__global__ void kPackMixW(const float* __restrict__ mwr, const float* __restrict__ mwi,
                          float2* __restrict__ wT2) {
  int idx = blockIdx.x * blockDim.x + threadIdx.x;
  if (idx >= MIXJ_ * H2_) return;
  int j = idx / H2_;
  int g = idx - j * H2_;
  wT2[idx] = make_float2(mwr[(size_t)g * MIXJ_ + j], mwi[(size_t)g * MIXJ_ + j]);
}

// ---------------------------------------------------------------------------
__launch_bounds__(128)
__global__ void kGather(const float* __restrict__ seq, const int* __restrict__ lead,
                        const int* __restrict__ shiftv, const float* __restrict__ r,
                        unsigned short* __restrict__ rhi, unsigned short* __restrict__ rlo) {
  int bc = blockIdx.x;
  int b = bc / C_;
  int lane = threadIdx.x;
#pragma unroll 1
  for (int k = 0; k < 17; k++) {
    float sg;
    const float* src;
    if (k < K_) {
      int ld = lead[(size_t)bc * K_ + k];
      int sh = shiftv[(size_t)bc * K_ + k];
      float rv = r[(size_t)bc * K_ + k];
      sg = (rv > 0.f) ? 1.f : ((rv < 0.f) ? -1.f : 0.f);
      src = seq + ((size_t)b * C_ + ld) * SEQLEN_ + (L_ - sh);
    } else {
      sg = 1.f;
      src = seq + (size_t)bc * SEQLEN_ + L_;
    }
    size_t mrow = (size_t)(bc * 17 + k) * 192;
#pragma unroll
    for (int p = 0; p < 2; p++) {
      int h = lane + p * 128;
      if (h < H_) {
        float v = src[h] * sg;
        unsigned short hh, ll;
        split_bf16(v, hh, ll);
        rhi[mrow + h] = hh;
        rlo[mrow + h] = ll;
      }
    }
  }
}

// ---------------------------------------------------------------------------
// kDFT: B staged in LDS in fragment order, 3 K-parts of 52 KB.
// ---------------------------------------------------------------------------
__launch_bounds__(256)
__global__ void kDFT(const unsigned short* __restrict__ rhi,
                     const unsigned short* __restrict__ rlo,
                     const unsigned short* __restrict__ bhi,
                     const unsigned short* __restrict__ blo,
                     float* __restrict__ F) {
  __shared__ __align__(16) unsigned short Bs[52 * 512];
  int tid = threadIdx.x;
  int wv = tid >> 6;
  int lane = tid & 63;
  int m0 = blockIdx.x * 64 + wv * 16;
  int row = lane & 15;
  int kg = lane >> 4;

  f32x4 acc[13];
#pragma unroll
  for (int nt = 0; nt < 13; nt++) acc[nt] = (f32x4){0.f, 0.f, 0.f, 0.f};

  const unsigned short* Ahb = rhi + (size_t)(m0 + row) * 192 + kg * 8;
  const unsigned short* Alb = rlo + (size_t)(m0 + row) * 192 + kg * 8;

#pragma unroll 1
  for (int part = 0; part < 3; part++) {
    __syncthreads();
    for (int s = tid >> 6; s < 52; s += 4) {
      int plane = s & 1;
      int ntks = s >> 1;
      int nt = ntks >> 1;
      int ks2 = ntks & 1;
      const unsigned short* src = (plane ? blo : bhi)
          + (size_t)(nt * 16 + row) * 192 + part * 64 + ks2 * 32 + kg * 8;
      *(bf16x8*)(Bs + s * 512 + lane * 8) = *(const bf16x8*)src;
    }
    __syncthreads();
#pragma unroll
    for (int ks2 = 0; ks2 < 2; ks2++) {
      int ksg = part * 2 + ks2;
      bf16x8 ah = *(const bf16x8*)(Ahb + ksg * 32);
      bf16x8 al = *(const bf16x8*)(Alb + ksg * 32);
#pragma unroll
      for (int nt = 0; nt < 13; nt++) {
        bf16x8 bh = *(const bf16x8*)(Bs + ((nt * 2 + ks2) * 2 + 0) * 512 + lane * 8);
        bf16x8 bl = *(const bf16x8*)(Bs + ((nt * 2 + ks2) * 2 + 1) * 512 + lane * 8);
        acc[nt] = __builtin_amdgcn_mfma_f32_16x16x32_bf16(ah, bh, acc[nt], 0, 0, 0);
        acc[nt] = __builtin_amdgcn_mfma_f32_16x16x32_bf16(ah, bl, acc[nt], 0, 0, 0);
        acc[nt] = __builtin_amdgcn_mfma_f32_16x16x32_bf16(al, bh, acc[nt], 0, 0, 0);
      }
    }
  }

  int crow0 = m0 + kg * 4;
#pragma unroll
  for (int nt = 0; nt < 13; nt++) {
#pragma unroll
    for (int rr = 0; rr < 4; rr++) {
      F[(size_t)(crow0 + rr) * NP_ + nt * 16 + row] = acc[nt][rr];
    }
  }
}

// ---------------------------------------------------------------------------
// kFiltMM: W2 tile staged in LDS (40 KB).
// ---------------------------------------------------------------------------
__launch_bounds__(256)
__global__ void kFiltMM(const unsigned short* __restrict__ uhi,
                        const unsigned short* __restrict__ ulo,
                        const unsigned short* __restrict__ w2hi,
                        const unsigned short* __restrict__ w2lo,
                        float* __restrict__ filt) {
  __shared__ __align__(16) unsigned short Ws[40 * 512];
  int tid = threadIdx.x;
  int wv = tid >> 6;
  int lane = tid & 63;
  int m0 = (blockIdx.y * 4 + wv) * 16;
  int n0 = blockIdx.x * 64;
  int col = lane & 15;
  int kg = lane >> 4;

  for (int s = tid >> 6; s < 40; s += 4) {
    int plane = s & 1;
    int ntk = s >> 1;
    int nt = ntk / 5;
    int ksi = ntk - nt * 5;
    const unsigned short* src = (plane ? w2lo : w2hi)
        + (size_t)(n0 + nt * 16 + col) * KF_ + ksi * 32 + kg * 8;
    *(bf16x8*)(Ws + s * 512 + lane * 8) = *(const bf16x8*)src;
  }
  __syncthreads();

  f32x4 acc[4];
#pragma unroll
  for (int nt = 0; nt < 4; nt++) acc[nt] = (f32x4){0.f, 0.f, 0.f, 0.f};

  int mrow = (m0 + col < MPADF_) ? (m0 + col) : (MPADF_ - 1);
  const unsigned short* Ah = uhi + (size_t)mrow * KF_ + kg * 8;
  const unsigned short* Al = ulo + (size_t)mrow * KF_ + kg * 8;

#pragma unroll
  for (int ks = 0; ks < 5; ks++) {
    bf16x8 ah = *(const bf16x8*)(Ah + ks * 32);
    bf16x8 al = *(const bf16x8*)(Al + ks * 32);
#pragma unroll
    for (int nt = 0; nt < 4; nt++) {
      bf16x8 bh = *(const bf16x8*)(Ws + ((nt * 5 + ks) * 2 + 0) * 512 + lane * 8);
      bf16x8 bl = *(const bf16x8*)(Ws + ((nt * 5 + ks) * 2 + 1) * 512 + lane * 8);
      acc[nt] = __builtin_amdgcn_mfma_f32_16x16x32_bf16(ah, bh, acc[nt], 0, 0, 0);
      acc[nt] = __builtin_amdgcn_mfma_f32_16x16x32_bf16(ah, bl, acc[nt], 0, 0, 0);
      acc[nt] = __builtin_amdgcn_mfma_f32_16x16x32_bf16(al, bh, acc[nt], 0, 0, 0);
    }
  }

  int crow0 = m0 + kg * 4;
#pragma unroll
  for (int nt = 0; nt < 4; nt++) {
    int o = n0 + nt * 16 + col;
    if (o < OUT_) {
#pragma unroll
      for (int rr = 0; rr < 4; rr++) {
        int m = crow0 + rr;
        if (m < BC_) filt[(size_t)m * OUT_ + o] = acc[nt][rr];
      }
    }
  }
}

// ---------------------------------------------------------------------------
// kPost2: 8 bc per block.  Phase1: combine->mix2(LDS).  Phase2: mix matmul
// (wT2 amortized 8x, 4-bc register accumulators).  Phase3: irfft + epilogue.
// ---------------------------------------------------------------------------
__launch_bounds__(256)
__global__ void kPost2(const float* __restrict__ F, const float* __restrict__ filt,
                       const float* __restrict__ seq,
                       const float* __restrict__ mu, const float* __restrict__ stdv,
                       const float2* __restrict__ wT2,
                       const float* __restrict__ mbr, const float* __restrict__ mbi,
                       float* __restrict__ out) {
  __shared__ __align__(16) v2f mix2[8][292];
  __shared__ float zrL[8][100], ziL[8][100];

  int tid = threadIdx.x;
  int half = tid >> 7;
  int ff = tid & 127;
  int bc0 = blockIdx.x * 8;

#pragma unroll 1
  for (int p = 0; p < 4; p++) {
    int bl = p * 2 + half;
    int bc = bc0 + bl;
    if (ff < H2_) {
      float Fre[17], Fim[17];
#pragma unroll
      for (int k = 0; k < 17; k++) {
        size_t mr = (size_t)(bc * 17 + k) * NP_;
        Fre[k] = F[mr + ff];
        Fim[k] = F[mr + 104 + ff];
      }
      const float* fb = filt + (size_t)bc * OUT_;
      float yfR = Fre[16], yfI = Fim[16];
      float S1r = 0.f, S1i = 0.f, S2r = 0.f, S2i = 0.f, sg2 = 0.f;
#pragma unroll
      for (int k = 0; k < K_; k++) {
        float g1 = fb[k * H2_ + ff];
        float g2 = fb[(K_ + k) * H2_ + ff];
        float g12 = g1 * g2;
        S1r = fmaf(Fre[k], g1, S1r);
        S1i = fmaf(Fim[k], g1, S1i);
        S2r = fmaf(Fre[k], g12, S2r);
        S2i = fmaf(Fim[k], g12, S2i);
        sg2 += g2;
      }
      S2r = fmaf(-yfR, sg2, S2r);
      S2i = fmaf(-yfI, sg2, S2i);
      float g3 = fb[32 * H2_ + ff];
      mix2[bl][ff] = (v2f){S1r, S1i};
      mix2[bl][H2_ + ff] = (v2f){S2r, S2i};
      mix2[bl][2 * H2_ + ff] = (v2f){yfR * g3, yfI * g3};
    }
  }
  __syncthreads();

  if (ff < H2_) {
    int g = ff;
    float zr_[4], zi_[4];
#pragma unroll
    for (int q = 0; q < 4; q++) { zr_[q] = mbr[g]; zi_[q] = mbi[g]; }
    const float2* wg = wT2 + g;
#pragma unroll 1
    for (int j = 0; j + 2 <= MIXJ_; j += 2) {
      float2 w0 = wg[(size_t)j * H2_];
      float2 w1 = wg[(size_t)(j + 1) * H2_];
#pragma unroll
      for (int q = 0; q < 4; q++) {
        v4f mm = *(const v4f*)&mix2[half * 4 + q][j];
        zr_[q] = fmaf(mm.x, w0.x, fmaf(-mm.y, w0.y, zr_[q]));
        zi_[q] = fmaf(mm.x, w0.y, fmaf(mm.y, w0.x, zi_[q]));
        zr_[q] = fmaf(mm.z, w1.x, fmaf(-mm.w, w1.y, zr_[q]));
        zi_[q] = fmaf(mm.z, w1.y, fmaf(mm.w, w1.x, zi_[q]));
      }
    }
    {
      int j = MIXJ_ - 1;
      float2 w0 = wg[(size_t)j * H2_];
#pragma unroll
      for (int q = 0; q < 4; q++) {
        v2f m2 = mix2[half * 4 + q][j];
        zr_[q] = fmaf(m2.x, w0.x, fmaf(-m2.y, w0.y, zr_[q]));
        zi_[q] = fmaf(m2.x, w0.y, fmaf(m2.y, w0.x, zi_[q]));
      }
    }
#pragma unroll
    for (int q = 0; q < 4; q++) {
      zrL[half * 4 + q][g] = zr_[q];
      ziL[half * 4 + q][g] = zi_[q];
    }
  }
  __syncthreads();

  if (ff < 96) {
    int h = ff;
    float ang = (TWO_PI_F / 192.f) * (float)h;
    float cs, sn;
    sincosf(ang, &sn, &cs);
#pragma unroll 1
    for (int q = 0; q < 4; q++) {
      int bl = half * 4 + q;
      int bc = bc0 + bl;
      int b = bc / C_;
      int c = bc - b * C_;
      float m = mu[bc], sd = stdv[bc];
      float base = 0.5f * zrL[bl][0] + ((h & 1) ? -0.5f : 0.5f) * zrL[bl][96];
      float aE = 0.f, aO = 0.f;
      float cv = cs, sv = sn;
      for (int fq = 1; fq < 96; fq += 2) {
        aO = fmaf(zrL[bl][fq], cv, fmaf(-ziL[bl][fq], sv, aO));
        float nc = cv * cs - sv * sn;
        float ns = cv * sn + sv * cs;
        aE = fmaf(zrL[bl][fq + 1], nc, fmaf(-ziL[bl][fq + 1], ns, aE));
        cv = nc * cs - ns * sn;
        sv = nc * sn + ns * cs;
      }
      float y0 = (base + aE + aO) * (2.f / 192.f);
      float y1 = (base + aE - aO) * (2.f / 192.f);
      const float* sq = seq + (size_t)bc * SEQLEN_ + L_;
      out[((size_t)b * H_ + h) * C_ + c] = fmaf(sq[h] + y0, sd, m);
      out[((size_t)b * H_ + h + 96) * C_ + c] = fmaf(sq[h + 96] + y1, sd, m);
    }
  }
}

// ---------------------------------------------------------------------------
extern "C" void kernel_launch(void* const* d_in, const int* in_sizes, int n_in,
                              void* d_out, int out_size, void* d_ws, size_t ws_size,
                              hipStream_t stream) {
  const float* x           = (const float*)d_in[0];
  const float* y_hat       = (const float*)d_in[1];
  const int*   lead        = (const int*)d_in[2];
  const int*   shiftv      = (const int*)d_in[3];
  const float* r           = (const float*)d_in[4];
  const float* temperature = (const float*)d_in[5];
  const float* cls_w       = (const float*)d_in[6];
  const float* cls_bias    = (const float*)d_in[7];
  const float* basic_state = (const float*)d_in[8];
  const float* mh_w        = (const float*)d_in[9];
  const float* mh_b        = (const float*)d_in[10];
  const float* mwr         = (const float*)d_in[11];
  const float* mwi         = (const float*)d_in[12];
  const float* mbr         = (const float*)d_in[13];
  const float* mbi         = (const float*)d_in[14];
  float* out = (float*)d_out;
  float* ws  = (float*)d_ws;

  unsigned short* bphi = (unsigned short*)(ws + OFF_BPHI);
  unsigned short* bplo = (unsigned short*)(ws + OFF_BPLO);
  unsigned short* uhi  = (unsigned short*)(ws + OFF_UHI);
  unsigned short* ulo  = (unsigned short*)(ws + OFF_ULO);
  unsigned short* w2hi = (unsigned short*)(ws + OFF_W2HI);
  unsigned short* w2lo = (unsigned short*)(ws + OFF_W2LO);
  unsigned short* rhi  = (unsigned short*)(ws + OFF_ROWS);
  unsigned short* rlo  = (unsigned short*)(ws + OFF_ROWSLO);

  dim3 gS(B_, 6);
  kStats<<<gS, 256, 0, stream>>>(x, cls_w, cls_bias, basic_state, r, temperature,
                                 ws + OFF_MU, ws + OFF_STD, uhi, ulo);

  dim3 gT(B_, 11, 17);
  kSeqT<<<gT, 256, 0, stream>>>(x, y_hat, ws + OFF_MU, ws + OFF_STD, ws + OFF_SEQ);

  kPackB<<<(NP_ * 192 + 255) / 256, 256, 0, stream>>>(bphi, bplo);

  kPackW2<<<(NPADF_ * KF_ + 255) / 256, 256, 0, stream>>>(mh_w, mh_b, w2hi, w2lo);

  kPackMixW<<<(MIXJ_ * H2_ + 255) / 256, 256, 0, stream>>>(
      mwr, mwi, (float2*)(ws + OFF_WT2));

  kGather<<<BC_, 128, 0, stream>>>(ws + OFF_SEQ, lead, shiftv, r, rhi, rlo);

  kDFT<<<NBLK_, 256, 0, stream>>>(rhi, rlo, bphi, bplo, ws + OFF_F);

  dim3 gFM(NPADF_ / 64, (MPADF_ / 16 + 3) / 4);
  kFiltMM<<<gFM, 256, 0, stream>>>(uhi, ulo, w2hi, w2lo, ws + OFF_FILT);

  kPost2<<<BC_ / 8, 256, 0, stream>>>(ws + OFF_F, ws + OFF_FILT, ws + OFF_SEQ,
                                      ws + OFF_MU, ws + OFF_STD,
                                      (const float2*)(ws + OFF_WT2), mbr, mbi, out);
}

// Round 10
// 226.972 us; speedup vs baseline: 1.4421x; 1.1259x over previous
//
#include <hip/hip_runtime.h>
#include <math.h>

#define B_ 8
#define L_ 336
#define H_ 192
#define C_ 321
#define K_ 16
#define S_ 8
#define H2_ 97
#define OUT_ 3201
#define SEQLEN_ 528
#define BC_ (B_ * C_)
#define JD_ 136
#define MIXJ_ 291
#define NP_ 208
#define MPAD_ 43712
#define NBLK_ 683
#define KF_ 160
#define MPADF_ 2576
#define NPADF_ 3264
#define KMX_ 608          // mix GEMM K: 291 re + 291 im + bias + pad
#define NMX_ 208          // mix GEMM N: 97 re | pad | 97 im @104
#define KIR_ 224          // irfft GEMM K (208 z cols + pad)
#define NIR_ 192          // irfft GEMM N (h)

typedef float v2f __attribute__((ext_vector_type(2)));
typedef float v4f __attribute__((ext_vector_type(4)));
typedef __attribute__((ext_vector_type(8))) short bf16x8;
typedef __attribute__((ext_vector_type(4))) float f32x4;

#define TWO_PI_F 6.283185307179586f

// ws layout (float units)
static constexpr size_t OFF_SEQ    = 0;
static constexpr size_t OFF_MU     = OFF_SEQ + (size_t)BC_ * SEQLEN_;
static constexpr size_t OFF_STD    = OFF_MU + BC_;
static constexpr size_t OFF_BPHI   = (OFF_STD + BC_ + 3) & ~(size_t)3;
static constexpr size_t OFF_BPLO   = OFF_BPHI + (size_t)NP_ * 192 / 2;
static constexpr size_t OFF_UHI    = (OFF_BPLO + (size_t)NP_ * 192 / 2 + 3) & ~(size_t)3;
static constexpr size_t OFF_ULO    = OFF_UHI + (size_t)MPADF_ * KF_ / 2;
static constexpr size_t OFF_W2HI   = OFF_ULO + (size_t)MPADF_ * KF_ / 2;
static constexpr size_t OFF_W2LO   = OFF_W2HI + (size_t)NPADF_ * KF_ / 2;
static constexpr size_t OFF_ROWS   = OFF_W2LO + (size_t)NPADF_ * KF_ / 2;
static constexpr size_t OFF_ROWSLO = OFF_ROWS + (size_t)MPAD_ * 192 / 2;
static constexpr size_t OFF_F      = OFF_ROWSLO + (size_t)MPAD_ * 192 / 2;
static constexpr size_t OFF_FILT   = OFF_ROWS;   // overlay: kFiltMM after kDFT
static constexpr size_t OFF_MWHI   = OFF_F + (size_t)MPAD_ * NP_;
static constexpr size_t OFF_MWLO   = OFF_MWHI + (size_t)NMX_ * KMX_ / 2;
static constexpr size_t OFF_THI    = OFF_MWLO + (size_t)NMX_ * KMX_ / 2;
static constexpr size_t OFF_TLO    = OFF_THI + (size_t)NIR_ * KIR_ / 2;
static constexpr size_t OFF_MXHI   = OFF_TLO + (size_t)NIR_ * KIR_ / 2;
static constexpr size_t OFF_MXLO   = OFF_MXHI + (size_t)MPADF_ * KMX_ / 2;
static constexpr size_t OFF_ZHI    = OFF_MXLO + (size_t)MPADF_ * KMX_ / 2;
static constexpr size_t OFF_ZLO    = OFF_ZHI + (size_t)MPADF_ * KIR_ / 2;
static constexpr size_t OFF_Y      = OFF_ZLO + (size_t)MPADF_ * KIR_ / 2;

__device__ inline void split_bf16(float v, unsigned short& hh, unsigned short& ll) {
  unsigned u = __float_as_uint(v);
  unsigned hb = (u + 0x7FFFu + ((u >> 16) & 1u)) & 0xFFFF0000u;
  float fh = __uint_as_float(hb);
  float fl = v - fh;
  unsigned u2 = __float_as_uint(fl);
  unsigned lb = (u2 + 0x7FFFu + ((u2 >> 16) & 1u)) >> 16;
  hh = (unsigned short)(hb >> 16);
  ll = (unsigned short)lb;
}

// ---------------------------------------------------------------------------
__launch_bounds__(256)
__global__ void kStats(const float* __restrict__ x, const float* __restrict__ cls_w,
                       const float* __restrict__ cls_bias,
                       const float* __restrict__ basic_state, const float* __restrict__ r,
                       const float* __restrict__ temperature,
                       float* __restrict__ mu, float* __restrict__ stdv,
                       unsigned short* __restrict__ uhi, unsigned short* __restrict__ ulo) {
  __shared__ float part[4][10][64];
  __shared__ float sp[64][S_];
  __shared__ float scf[64][K_];

  int b = blockIdx.x;
  int cb = blockIdx.y * 64;
  int lane = threadIdx.x & 63;
  int wv = threadIdx.x >> 6;
  int c = cb + lane;
  bool cok = c < C_;

  float sum = 0.f, sumsq = 0.f, a[S_];
#pragma unroll
  for (int s = 0; s < S_; s++) a[s] = 0.f;
  if (cok) {
    for (int l = wv * 84; l < wv * 84 + 84; l++) {
      float v = x[((size_t)b * L_ + l) * C_ + c];
      sum += v;
      sumsq = fmaf(v, v, sumsq);
#pragma unroll
      for (int s = 0; s < S_; s++) a[s] = fmaf(v, cls_w[s * L_ + l], a[s]);
    }
  }
  part[wv][0][lane] = sum;
  part[wv][1][lane] = sumsq;
#pragma unroll
  for (int s = 0; s < S_; s++) part[wv][2 + s][lane] = a[s];
  __syncthreads();

  if (threadIdx.x < 64 && cok) {
    float s0 = 0.f, s1 = 0.f, ac[S_];
#pragma unroll
    for (int s = 0; s < S_; s++) ac[s] = 0.f;
#pragma unroll
    for (int w = 0; w < 4; w++) {
      s0 += part[w][0][lane];
      s1 += part[w][1][lane];
#pragma unroll
      for (int s = 0; s < S_; s++) ac[s] += part[w][2 + s][lane];
    }
    float m = s0 * (1.f / L_);
    float var = fmaxf(s1 * (1.f / L_) - m * m, 0.f);
    float sd = sqrtf(var + 1e-8f);
    int bc = b * C_ + c;
    mu[bc] = m;
    stdv[bc] = sd;

    float lg[S_], mx = -1e30f;
#pragma unroll
    for (int s = 0; s < S_; s++) {
      lg[s] = ac[s] + cls_bias[s] + basic_state[c * S_ + s];
      mx = fmaxf(mx, lg[s]);
    }
    float den = 0.f;
#pragma unroll
    for (int s = 0; s < S_; s++) { float e = expf(lg[s] - mx); lg[s] = e; den += e; }
    float iden = 1.f / den;
#pragma unroll
    for (int s = 0; s < S_; s++) sp[lane][s] = lg[s] * iden;

    float it = 1.f / temperature[0];
    float aa[K_], am = it;
#pragma unroll
    for (int k = 0; k < K_; k++) {
      aa[k] = fabsf(r[(size_t)bc * K_ + k]) * it;
      am = fmaxf(am, aa[k]);
    }
    float den2 = expf(it - am);
#pragma unroll
    for (int k = 0; k < K_; k++) { float e = expf(aa[k] - am); aa[k] = e; den2 += e; }
    float iden2 = 1.f / den2;
#pragma unroll
    for (int k = 0; k < K_; k++) scf[lane][k] = aa[k] * iden2;
  }
  __syncthreads();

  for (int idx = threadIdx.x; idx < 64 * KF_; idx += 256) {
    int ci = idx / KF_;
    int j = idx - ci * KF_;
    if (cb + ci < C_) {
      float v = 0.f;
      if (j < JD_) {
        int s = j / 17;
        int t = j - s * 17;
        v = sp[ci][s];
        if (t < K_) v *= scf[ci][t];
      }
      unsigned short hh, ll;
      split_bf16(v, hh, ll);
      size_t row = (size_t)(b * C_ + cb + ci) * KF_ + j;
      uhi[row] = hh;
      ulo[row] = ll;
    }
  }
}

// ---------------------------------------------------------------------------
__launch_bounds__(256)
__global__ void kSeqT(const float* __restrict__ x, const float* __restrict__ y_hat,
                      const float* __restrict__ mu, const float* __restrict__ stdv,
                      float* __restrict__ seq) {
  __shared__ float tile[32][33];
  int b = blockIdx.x;
  int cb = blockIdx.y * 32;
  int tb = blockIdx.z * 32;
  int ci = threadIdx.x & 31;
  int q8 = threadIdx.x >> 5;
  int c = cb + ci;
  float m = 0.f, is = 0.f;
  if (c < C_) {
    m = mu[b * C_ + c];
    is = 1.f / stdv[b * C_ + c];
  }
#pragma unroll
  for (int q = 0; q < 4; q++) {
    int tt = q8 + q * 8;
    int t = tb + tt;
    float v = 0.f;
    if (c < C_ && t < SEQLEN_)
      v = (t < L_) ? x[((size_t)b * L_ + t) * C_ + c]
                   : y_hat[((size_t)b * H_ + (t - L_)) * C_ + c];
    tile[ci][tt] = (v - m) * is;
  }
  __syncthreads();
#pragma unroll
  for (int q = 0; q < 4; q++) {
    int cc = cb + q8 + q * 8;
    int t = tb + ci;
    if (cc < C_ && t < SEQLEN_)
      seq[((size_t)b * C_ + cc) * SEQLEN_ + t] = tile[q8 + q * 8][ci];
  }
}

// ---------------------------------------------------------------------------
__global__ void kPackB(unsigned short* __restrict__ bhi, unsigned short* __restrict__ blo) {
  int idx = blockIdx.x * 256 + threadIdx.x;
  if (idx >= NP_ * 192) return;
  int n = idx / 192;
  int h = idx - n * 192;
  float val = 0.f;
  if (n < H2_) {
    int ph = (n * h) % 192;
    val = cosf((TWO_PI_F / 192.f) * (float)ph);
  } else if (n >= 104 && n < 104 + H2_) {
    int ph = ((n - 104) * h) % 192;
    val = -sinf((TWO_PI_F / 192.f) * (float)ph);
  }
  unsigned short hh, ll;
  split_bf16(val, hh, ll);
  bhi[idx] = hh;
  blo[idx] = ll;
}

// ---------------------------------------------------------------------------
__global__ void kPackW2(const float* __restrict__ mh_w, const float* __restrict__ mh_b,
                        unsigned short* __restrict__ w2hi, unsigned short* __restrict__ w2lo) {
  int idx = blockIdx.x * 256 + threadIdx.x;
  if (idx >= NPADF_ * KF_) return;
  int n = idx / KF_;
  int k = idx - n * KF_;
  float v = 0.f;
  if (n < OUT_ && k < JD_) {
    int s = k / 17;
    int t = k - s * 17;
    v = (t < K_) ? mh_w[(size_t)s * (K_ * OUT_) + (size_t)t * OUT_ + n]
                 : mh_b[(size_t)s * OUT_ + n];
  }
  unsigned short hh, ll;
  split_bf16(v, hh, ll);
  w2hi[idx] = hh;
  w2lo[idx] = ll;
}

// ---------------------------------------------------------------------------
// kPackMixW2: mix GEMM B, n-major [NMX_][KMX_] bf16 hi/lo.
// n<97 (Re row g=n):   k<291: wr[g][k];  k in [291,582): -wi[g][k-291]; k==582: mbr[g]
// n in [104,201) (Im): k<291: wi[g][k];  k in [291,582):  wr[g][k-291]; k==582: mbi[g]
// ---------------------------------------------------------------------------
__global__ void kPackMixW2(const float* __restrict__ mwr, const float* __restrict__ mwi,
                           const float* __restrict__ mbr, const float* __restrict__ mbi,
                           unsigned short* __restrict__ mwhi, unsigned short* __restrict__ mwlo) {
  int idx = blockIdx.x * 256 + threadIdx.x;
  if (idx >= NMX_ * KMX_) return;
  int n = idx / KMX_;
  int k = idx - n * KMX_;
  float v = 0.f;
  if (n < H2_) {
    int g = n;
    if (k < MIXJ_) v = mwr[(size_t)g * MIXJ_ + k];
    else if (k < 2 * MIXJ_) v = -mwi[(size_t)g * MIXJ_ + (k - MIXJ_)];
    else if (k == 2 * MIXJ_) v = mbr[g];
  } else if (n >= 104 && n < 104 + H2_) {
    int g = n - 104;
    if (k < MIXJ_) v = mwi[(size_t)g * MIXJ_ + k];
    else if (k < 2 * MIXJ_) v = mwr[(size_t)g * MIXJ_ + (k - MIXJ_)];
    else if (k == 2 * MIXJ_) v = mbi[g];
  }
  unsigned short hh, ll;
  split_bf16(v, hh, ll);
  mwhi[idx] = hh;
  mwlo[idx] = ll;
}

// ---------------------------------------------------------------------------
// kPackT: irfft GEMM B, n-major [NIR_][KIR_] bf16 hi/lo.
// row h, col k: k<97 (f=k): w_f*cos(2pi f h/192), w=1/192 for f=0,96 else 2/192
//               k in [104,201) (f=k-104): f==0||96 ? 0 : -(2/192)*sin(2pi f h/192)
// ---------------------------------------------------------------------------
__global__ void kPackT(unsigned short* __restrict__ thi, unsigned short* __restrict__ tlo) {
  int idx = blockIdx.x * 256 + threadIdx.x;
  if (idx >= NIR_ * KIR_) return;
  int h = idx / KIR_;
  int k = idx - h * KIR_;
  float v = 0.f;
  if (k < H2_) {
    int f = k;
    float w = (f == 0 || f == 96) ? (1.f / 192.f) : (2.f / 192.f);
    int ph = (f * h) % 192;
    v = w * cosf((TWO_PI_F / 192.f) * (float)ph);
  } else if (k >= 104 && k < 104 + H2_) {
    int f = k - 104;
    if (f != 0 && f != 96) {
      int ph = (f * h) % 192;
      v = -(2.f / 192.f) * sinf((TWO_PI_F / 192.f) * (float)ph);
    }
  }
  unsigned short hh, ll;
  split_bf16(v, hh, ll);
  thi[idx] = hh;
  tlo[idx] = ll;
}

// ---------------------------------------------------------------------------
__launch_bounds__(128)
__global__ void kGather(const float* __restrict__ seq, const int* __restrict__ lead,
                        const int* __restrict__ shiftv, const float* __restrict__ r,
                        unsigned short* __restrict__ rhi, unsigned short* __restrict__ rlo) {
  int bc = blockIdx.x;
  int b = bc / C_;
  int lane = threadIdx.x;
#pragma unroll 1
  for (int k = 0; k < 17; k++) {
    float sg;
    const float* src;
    if (k < K_) {
      int ld = lead[(size_t)bc * K_ + k];
      int sh = shiftv[(size_t)bc * K_ + k];
      float rv = r[(size_t)bc * K_ + k];
      sg = (rv > 0.f) ? 1.f : ((rv < 0.f) ? -1.f : 0.f);
      src = seq + ((size_t)b * C_ + ld) * SEQLEN_ + (L_ - sh);
    } else {
      sg = 1.f;
      src = seq + (size_t)bc * SEQLEN_ + L_;
    }
    size_t mrow = (size_t)(bc * 17 + k) * 192;
#pragma unroll
    for (int p = 0; p < 2; p++) {
      int h = lane + p * 128;
      if (h < H_) {
        float v = src[h] * sg;
        unsigned short hh, ll;
        split_bf16(v, hh, ll);
        rhi[mrow + h] = hh;
        rlo[mrow + h] = ll;
      }
    }
  }
}

// ---------------------------------------------------------------------------
// kDFT: B staged in LDS in fragment order, 3 K-parts of 52 KB.
// ---------------------------------------------------------------------------
__launch_bounds__(256)
__global__ void kDFT(const unsigned short* __restrict__ rhi,
                     const unsigned short* __restrict__ rlo,
                     const unsigned short* __restrict__ bhi,
                     const unsigned short* __restrict__ blo,
                     float* __restrict__ F) {
  __shared__ __align__(16) unsigned short Bs[52 * 512];
  int tid = threadIdx.x;
  int wv = tid >> 6;
  int lane = tid & 63;
  int m0 = blockIdx.x * 64 + wv * 16;
  int row = lane & 15;
  int kg = lane >> 4;

  f32x4 acc[13];
#pragma unroll
  for (int nt = 0; nt < 13; nt++) acc[nt] = (f32x4){0.f, 0.f, 0.f, 0.f};

  const unsigned short* Ahb = rhi + (size_t)(m0 + row) * 192 + kg * 8;
  const unsigned short* Alb = rlo + (size_t)(m0 + row) * 192 + kg * 8;

#pragma unroll 1
  for (int part = 0; part < 3; part++) {
    __syncthreads();
    for (int s = tid >> 6; s < 52; s += 4) {
      int plane = s & 1;
      int ntks = s >> 1;
      int nt = ntks >> 1;
      int ks2 = ntks & 1;
      const unsigned short* src = (plane ? blo : bhi)
          + (size_t)(nt * 16 + row) * 192 + part * 64 + ks2 * 32 + kg * 8;
      *(bf16x8*)(Bs + s * 512 + lane * 8) = *(const bf16x8*)src;
    }
    __syncthreads();
#pragma unroll
    for (int ks2 = 0; ks2 < 2; ks2++) {
      int ksg = part * 2 + ks2;
      bf16x8 ah = *(const bf16x8*)(Ahb + ksg * 32);
      bf16x8 al = *(const bf16x8*)(Alb + ksg * 32);
#pragma unroll
      for (int nt = 0; nt < 13; nt++) {
        bf16x8 bh = *(const bf16x8*)(Bs + ((nt * 2 + ks2) * 2 + 0) * 512 + lane * 8);
        bf16x8 bl = *(const bf16x8*)(Bs + ((nt * 2 + ks2) * 2 + 1) * 512 + lane * 8);
        acc[nt] = __builtin_amdgcn_mfma_f32_16x16x32_bf16(ah, bh, acc[nt], 0, 0, 0);
        acc[nt] = __builtin_amdgcn_mfma_f32_16x16x32_bf16(ah, bl, acc[nt], 0, 0, 0);
        acc[nt] = __builtin_amdgcn_mfma_f32_16x16x32_bf16(al, bh, acc[nt], 0, 0, 0);
      }
    }
  }

  int crow0 = m0 + kg * 4;
#pragma unroll
  for (int nt = 0; nt < 13; nt++) {
#pragma unroll
    for (int rr = 0; rr < 4; rr++) {
      F[(size_t)(crow0 + rr) * NP_ + nt * 16 + row] = acc[nt][rr];
    }
  }
}

// ---------------------------------------------------------------------------
// kFiltMM: W2 tile staged in LDS (40 KB).
// ---------------------------------------------------------------------------
__launch_bounds__(256)
__global__ void kFiltMM(const unsigned short* __restrict__ uhi,
                        const unsigned short* __restrict__ ulo,
                        const unsigned short* __restrict__ w2hi,
                        const unsigned short* __restrict__ w2lo,
                        float* __restrict__ filt) {
  __shared__ __align__(16) unsigned short Ws[40 * 512];
  int tid = threadIdx.x;
  int wv = tid >> 6;
  int lane = tid & 63;
  int m0 = (blockIdx.y * 4 + wv) * 16;
  int n0 = blockIdx.x * 64;
  int col = lane & 15;
  int kg = lane >> 4;

  for (int s = tid >> 6; s < 40; s += 4) {
    int plane = s & 1;
    int ntk = s >> 1;
    int nt = ntk / 5;
    int ksi = ntk - nt * 5;
    const unsigned short* src = (plane ? w2lo : w2hi)
        + (size_t)(n0 + nt * 16 + col) * KF_ + ksi * 32 + kg * 8;
    *(bf16x8*)(Ws + s * 512 + lane * 8) = *(const bf16x8*)src;
  }
  __syncthreads();

  f32x4 acc[4];
#pragma unroll
  for (int nt = 0; nt < 4; nt++) acc[nt] = (f32x4){0.f, 0.f, 0.f, 0.f};

  int mrow = (m0 + col < MPADF_) ? (m0 + col) : (MPADF_ - 1);
  const unsigned short* Ah = uhi + (size_t)mrow * KF_ + kg * 8;
  const unsigned short* Al = ulo + (size_t)mrow * KF_ + kg * 8;

#pragma unroll
  for (int ks = 0; ks < 5; ks++) {
    bf16x8 ah = *(const bf16x8*)(Ah + ks * 32);
    bf16x8 al = *(const bf16x8*)(Al + ks * 32);
#pragma unroll
    for (int nt = 0; nt < 4; nt++) {
      bf16x8 bh = *(const bf16x8*)(Ws + ((nt * 5 + ks) * 2 + 0) * 512 + lane * 8);
      bf16x8 bl = *(const bf16x8*)(Ws + ((nt * 5 + ks) * 2 + 1) * 512 + lane * 8);
      acc[nt] = __builtin_amdgcn_mfma_f32_16x16x32_bf16(ah, bh, acc[nt], 0, 0, 0);
      acc[nt] = __builtin_amdgcn_mfma_f32_16x16x32_bf16(ah, bl, acc[nt], 0, 0, 0);
      acc[nt] = __builtin_amdgcn_mfma_f32_16x16x32_bf16(al, bh, acc[nt], 0, 0, 0);
    }
  }

  int crow0 = m0 + kg * 4;
#pragma unroll
  for (int nt = 0; nt < 4; nt++) {
    int o = n0 + nt * 16 + col;
    if (o < OUT_) {
#pragma unroll
      for (int rr = 0; rr < 4; rr++) {
        int m = crow0 + rr;
        if (m < BC_) filt[(size_t)m * OUT_ + o] = acc[nt][rr];
      }
    }
  }
}

// ---------------------------------------------------------------------------
// kCombine: per bc (128 thr, grid 2568): filt combine -> mix_in bf16 planes.
// K layout: [0,97) S1r | [97,194) S2r | [194,291) YgR | [291,388) S1i |
//           [388,485) S2i | [485,582) YgI | 582: 1.0 (bias) | rest 0.
// ---------------------------------------------------------------------------
__launch_bounds__(128)
__global__ void kCombine(const float* __restrict__ F, const float* __restrict__ filt,
                         unsigned short* __restrict__ mxhi, unsigned short* __restrict__ mxlo) {
  int bc = blockIdx.x;
  int ff = threadIdx.x;
  size_t mrowK = (size_t)bc * KMX_;

  if (ff < H2_) {
    float Fre[17], Fim[17];
#pragma unroll
    for (int k = 0; k < 17; k++) {
      size_t mr = (size_t)(bc * 17 + k) * NP_;
      Fre[k] = F[mr + ff];
      Fim[k] = F[mr + 104 + ff];
    }
    const float* fb = filt + (size_t)bc * OUT_;
    float yfR = Fre[16], yfI = Fim[16];
    float S1r = 0.f, S1i = 0.f, S2r = 0.f, S2i = 0.f, sg2 = 0.f;
#pragma unroll
    for (int k = 0; k < K_; k++) {
      float g1 = fb[k * H2_ + ff];
      float g2 = fb[(K_ + k) * H2_ + ff];
      float g12 = g1 * g2;
      S1r = fmaf(Fre[k], g1, S1r);
      S1i = fmaf(Fim[k], g1, S1i);
      S2r = fmaf(Fre[k], g12, S2r);
      S2i = fmaf(Fim[k], g12, S2i);
      sg2 += g2;
    }
    S2r = fmaf(-yfR, sg2, S2r);
    S2i = fmaf(-yfI, sg2, S2i);
    float g3 = fb[32 * H2_ + ff];
    float vals[6] = {S1r, S2r, yfR * g3, S1i, S2i, yfI * g3};
#pragma unroll
    for (int q = 0; q < 6; q++) {
      unsigned short hh, ll;
      split_bf16(vals[q], hh, ll);
      mxhi[mrowK + q * H2_ + ff] = hh;
      mxlo[mrowK + q * H2_ + ff] = ll;
    }
  } else if (ff == H2_) {
    // bias element k = 582
    mxhi[mrowK + 2 * MIXJ_] = 0x3F80;  // bf16(1.0)
    mxlo[mrowK + 2 * MIXJ_] = 0;
  } else if (ff >= 98 && ff < 98 + (KMX_ - 583)) {
    int k = 583 + (ff - 98);
    mxhi[mrowK + k] = 0;
    mxlo[mrowK + k] = 0;
  }
}

// ---------------------------------------------------------------------------
// kMixMM: z GEMM.  M=2576, N=208 (13 nt), K=608 (19 ks).  grid (13, 41).
// Block = 4 waves x 16 m-rows, one nt; B slice staged in LDS (38 KB).
// Output z as bf16 hi/lo planes [MPADF_][KIR_], cols 208..223 zeroed.
// ---------------------------------------------------------------------------
__launch_bounds__(256)
__global__ void kMixMM(const unsigned short* __restrict__ mxhi,
                       const unsigned short* __restrict__ mxlo,
                       const unsigned short* __restrict__ mwhi,
                       const unsigned short* __restrict__ mwlo,
                       unsigned short* __restrict__ zhi, unsigned short* __restrict__ zlo) {
  __shared__ __align__(16) unsigned short Bs[38 * 512];
  int tid = threadIdx.x;
  int wv = tid >> 6;
  int lane = tid & 63;
  int nt = blockIdx.x;
  int m0 = (blockIdx.y * 4 + wv) * 16;
  int row = lane & 15;
  int kg = lane >> 4;

  for (int s = wv; s < 38; s += 4) {
    int plane = s & 1;
    int ks = s >> 1;
    const unsigned short* src = (plane ? mwlo : mwhi)
        + (size_t)(nt * 16 + row) * KMX_ + ks * 32 + kg * 8;
    *(bf16x8*)(Bs + s * 512 + lane * 8) = *(const bf16x8*)src;
  }
  __syncthreads();

  if (m0 >= MPADF_) return;

  f32x4 acc = (f32x4){0.f, 0.f, 0.f, 0.f};
  const unsigned short* Ah = mxhi + (size_t)(m0 + row) * KMX_ + kg * 8;
  const unsigned short* Al = mxlo + (size_t)(m0 + row) * KMX_ + kg * 8;

#pragma unroll
  for (int ks = 0; ks < 19; ks++) {
    bf16x8 ah = *(const bf16x8*)(Ah + ks * 32);
    bf16x8 al = *(const bf16x8*)(Al + ks * 32);
    bf16x8 bh = *(const bf16x8*)(Bs + (ks * 2 + 0) * 512 + lane * 8);
    bf16x8 bl = *(const bf16x8*)(Bs + (ks * 2 + 1) * 512 + lane * 8);
    acc = __builtin_amdgcn_mfma_f32_16x16x32_bf16(ah, bh, acc, 0, 0, 0);
    acc = __builtin_amdgcn_mfma_f32_16x16x32_bf16(ah, bl, acc, 0, 0, 0);
    acc = __builtin_amdgcn_mfma_f32_16x16x32_bf16(al, bh, acc, 0, 0, 0);
  }

  int crow0 = m0 + kg * 4;
#pragma unroll
  for (int rr = 0; rr < 4; rr++) {
    unsigned short hh, ll;
    split_bf16(acc[rr], hh, ll);
    zhi[(size_t)(crow0 + rr) * KIR_ + nt * 16 + row] = hh;
    zlo[(size_t)(crow0 + rr) * KIR_ + nt * 16 + row] = ll;
  }
  if (nt == 12) {
    for (int cc = 208 + kg; cc < KIR_; cc += 4) {
      zhi[(size_t)(m0 + row) * KIR_ + cc] = 0;
      zlo[(size_t)(m0 + row) * KIR_ + cc] = 0;
    }
  }
}

// ---------------------------------------------------------------------------
// kIrfft: y GEMM.  M=2576, N=192 (12 nt), K=224 (7 ks).  grid (12, 41).
// B slice (T) staged in LDS (14 KB).  Output y f32 [MPADF_][192].
// ---------------------------------------------------------------------------
__launch_bounds__(256)
__global__ void kIrfft(const unsigned short* __restrict__ zhi,
                       const unsigned short* __restrict__ zlo,
                       const unsigned short* __restrict__ thi,
                       const unsigned short* __restrict__ tlo,
                       float* __restrict__ y) {
  __shared__ __align__(16) unsigned short Bs[14 * 512];
  int tid = threadIdx.x;
  int wv = tid >> 6;
  int lane = tid & 63;
  int nt = blockIdx.x;
  int m0 = (blockIdx.y * 4 + wv) * 16;
  int row = lane & 15;
  int kg = lane >> 4;

  for (int s = wv; s < 14; s += 4) {
    int plane = s & 1;
    int ks = s >> 1;
    const unsigned short* src = (plane ? tlo : thi)
        + (size_t)(nt * 16 + row) * KIR_ + ks * 32 + kg * 8;
    *(bf16x8*)(Bs + s * 512 + lane * 8) = *(const bf16x8*)src;
  }
  __syncthreads();

  if (m0 >= MPADF_) return;

  f32x4 acc = (f32x4){0.f, 0.f, 0.f, 0.f};
  const unsigned short* Ah = zhi + (size_t)(m0 + row) * KIR_ + kg * 8;
  const unsigned short* Al = zlo + (size_t)(m0 + row) * KIR_ + kg * 8;

#pragma unroll
  for (int ks = 0; ks < 7; ks++) {
    bf16x8 ah = *(const bf16x8*)(Ah + ks * 32);
    bf16x8 al = *(const bf16x8*)(Al + ks * 32);
    bf16x8 bh = *(const bf16x8*)(Bs + (ks * 2 + 0) * 512 + lane * 8);
    bf16x8 bl = *(const bf16x8*)(Bs + (ks * 2 + 1) * 512 + lane * 8);
    acc = __builtin_amdgcn_mfma_f32_16x16x32_bf16(ah, bh, acc, 0, 0, 0);
    acc = __builtin_amdgcn_mfma_f32_16x16x32_bf16(ah, bl, acc, 0, 0, 0);
    acc = __builtin_amdgcn_mfma_f32_16x16x32_bf16(al, bh, acc, 0, 0, 0);
  }

  int crow0 = m0 + kg * 4;
#pragma unroll
  for (int rr = 0; rr < 4; rr++) {
    y[(size_t)(crow0 + rr) * NIR_ + nt * 16 + row] = acc[rr];
  }
}

// ---------------------------------------------------------------------------
// kEpi: out[(b*H+h)*C+c] = (yhn[bc][h] + y[bc][h]) * sd + mu, 32x32 transpose.
// grid (B_, 11, 6), block 256.
// ---------------------------------------------------------------------------
__launch_bounds__(256)
__global__ void kEpi(const float* __restrict__ y, const float* __restrict__ seq,
                     const float* __restrict__ mu, const float* __restrict__ stdv,
                     float* __restrict__ out) {
  __shared__ float tile[32][33];
  int b = blockIdx.x;
  int cb = blockIdx.y * 32;
  int hb = blockIdx.z * 32;
  int lane5 = threadIdx.x & 31;
  int q8 = threadIdx.x >> 5;

#pragma unroll
  for (int q = 0; q < 4; q++) {
    int cc = q8 + q * 8;
    int c = cb + cc;
    float v = 0.f;
    if (c < C_) {
      size_t bc = (size_t)b * C_ + c;
      v = y[bc * NIR_ + hb + lane5] + seq[bc * SEQLEN_ + L_ + hb + lane5];
    }
    tile[cc][lane5] = v;
  }
  __syncthreads();

  int c2 = cb + lane5;
  if (c2 < C_) {
    float m = mu[b * C_ + c2];
    float sd = stdv[b * C_ + c2];
#pragma unroll
    for (int q = 0; q < 4; q++) {
      int hh = q8 + q * 8;
      out[((size_t)b * H_ + hb + hh) * C_ + c2] = fmaf(tile[lane5][hh], sd, m);
    }
  }
}

// ---------------------------------------------------------------------------
extern "C" void kernel_launch(void* const* d_in, const int* in_sizes, int n_in,
                              void* d_out, int out_size, void* d_ws, size_t ws_size,
                              hipStream_t stream) {
  const float* x           = (const float*)d_in[0];
  const float* y_hat       = (const float*)d_in[1];
  const int*   lead        = (const int*)d_in[2];
  const int*   shiftv      = (const int*)d_in[3];
  const float* r           = (const float*)d_in[4];
  const float* temperature = (const float*)d_in[5];
  const float* cls_w       = (const float*)d_in[6];
  const float* cls_bias    = (const float*)d_in[7];
  const float* basic_state = (const float*)d_in[8];
  const float* mh_w        = (const float*)d_in[9];
  const float* mh_b        = (const float*)d_in[10];
  const float* mwr         = (const float*)d_in[11];
  const float* mwi         = (const float*)d_in[12];
  const float* mbr         = (const float*)d_in[13];
  const float* mbi         = (const float*)d_in[14];
  float* out = (float*)d_out;
  float* ws  = (float*)d_ws;

  unsigned short* bphi = (unsigned short*)(ws + OFF_BPHI);
  unsigned short* bplo = (unsigned short*)(ws + OFF_BPLO);
  unsigned short* uhi  = (unsigned short*)(ws + OFF_UHI);
  unsigned short* ulo  = (unsigned short*)(ws + OFF_ULO);
  unsigned short* w2hi = (unsigned short*)(ws + OFF_W2HI);
  unsigned short* w2lo = (unsigned short*)(ws + OFF_W2LO);
  unsigned short* rhi  = (unsigned short*)(ws + OFF_ROWS);
  unsigned short* rlo  = (unsigned short*)(ws + OFF_ROWSLO);
  unsigned short* mwhi = (unsigned short*)(ws + OFF_MWHI);
  unsigned short* mwlo = (unsigned short*)(ws + OFF_MWLO);
  unsigned short* thi  = (unsigned short*)(ws + OFF_THI);
  unsigned short* tlo  = (unsigned short*)(ws + OFF_TLO);
  unsigned short* mxhi = (unsigned short*)(ws + OFF_MXHI);
  unsigned short* mxlo = (unsigned short*)(ws + OFF_MXLO);
  unsigned short* zhi  = (unsigned short*)(ws + OFF_ZHI);
  unsigned short* zlo  = (unsigned short*)(ws + OFF_ZLO);

  dim3 gS(B_, 6);
  kStats<<<gS, 256, 0, stream>>>(x, cls_w, cls_bias, basic_state, r, temperature,
                                 ws + OFF_MU, ws + OFF_STD, uhi, ulo);

  dim3 gT(B_, 11, 17);
  kSeqT<<<gT, 256, 0, stream>>>(x, y_hat, ws + OFF_MU, ws + OFF_STD, ws + OFF_SEQ);

  kPackB<<<(NP_ * 192 + 255) / 256, 256, 0, stream>>>(bphi, bplo);
  kPackW2<<<(NPADF_ * KF_ + 255) / 256, 256, 0, stream>>>(mh_w, mh_b, w2hi, w2lo);
  kPackMixW2<<<(NMX_ * KMX_ + 255) / 256, 256, 0, stream>>>(mwr, mwi, mbr, mbi, mwhi, mwlo);
  kPackT<<<(NIR_ * KIR_ + 255) / 256, 256, 0, stream>>>(thi, tlo);

  kGather<<<BC_, 128, 0, stream>>>(ws + OFF_SEQ, lead, shiftv, r, rhi, rlo);

  kDFT<<<NBLK_, 256, 0, stream>>>(rhi, rlo, bphi, bplo, ws + OFF_F);

  dim3 gFM(NPADF_ / 64, (MPADF_ / 16 + 3) / 4);
  kFiltMM<<<gFM, 256, 0, stream>>>(uhi, ulo, w2hi, w2lo, ws + OFF_FILT);

  kCombine<<<BC_, 128, 0, stream>>>(ws + OFF_F, ws + OFF_FILT, mxhi, mxlo);

  dim3 gMX(13, 41);
  kMixMM<<<gMX, 256, 0, stream>>>(mxhi, mxlo, mwhi, mwlo, zhi, zlo);

  dim3 gIR(12, 41);
  kIrfft<<<gIR, 256, 0, stream>>>(zhi, zlo, thi, tlo, ws + OFF_Y);

  dim3 gE(B_, 11, 6);
  kEpi<<<gE, 256, 0, stream>>>(ws + OFF_Y, ws + OFF_SEQ, ws + OFF_MU, ws + OFF_STD, out);
}